// Round 10
// baseline (313.853 us; speedup 1.0000x reference)
//
#include <hip/hip_runtime.h>
#include <hip/hip_bf16.h>

// S4 (DPLR) forward, B=8 L=2048 IN=OUT=64 H=128 N=64, 4 layers.
// R26 = R25 + conv restructured as per-(h,batch) real-signal conv via half-size
// FFT: z_n = u_{2n}+i*u_{2n+1} (upper half zero -> pruned), fwd 2048-pt FFT
// (radix 8*8*8*4, all 256 threads busy every pass), Hermitian pair phase
// (U_k = A+W^k B; V=U*Kd; repack E+iO), inverse, unpack. Grid 1024 blocks ->
// 16 waves/CU (2x the complex-pair conv), 16KB LDS/block, half per-phase work.
// Kd now stored in NATURAL bin order by kfft (R24-verified slot formula, with
// arithmetic bit-reversal instead of table loads - tables were R24's regression).
// Swizzle sw2(i)=i^((i>>4)&15) keeps strides 256/32/4/1 at <=4-way conflicts.
// omega via cosf/sinf on purpose (l=1024 bilinear singularity, see kfft_core).

#define Bsz 8
#define Lseq 2048
#define Hdim 128
#define Npol 64
#define NLAYERS 4

typedef __bf16 bf16x8 __attribute__((ext_vector_type(8)));
typedef float f32x16 __attribute__((ext_vector_type(16)));

__device__ __forceinline__ float fast_rcp(float x) { return __builtin_amdgcn_rcpf(x); }
__device__ __forceinline__ float fast_rsq(float x) { return __builtin_amdgcn_rsqf(x); }

__device__ __forceinline__ float2 cmulf(float2 a, float2 b) {
    return make_float2(a.x * b.x - a.y * b.y, a.x * b.y + a.y * b.x);
}
__device__ __forceinline__ float2 cmulc(float2 a, float2 b) {  // a * conj(b)
    return make_float2(a.x * b.x + a.y * b.y, a.y * b.x - a.x * b.y);
}
__device__ __forceinline__ float2 cadd(float2 a, float2 b) {
    return make_float2(a.x + b.x, a.y + b.y);
}
__device__ __forceinline__ float2 csub(float2 a, float2 b) {
    return make_float2(a.x - b.x, a.y - b.y);
}

__device__ __forceinline__ float gelu_f(float v) {
    float z = 0.7978845608028654f * (v + 0.044715f * v * v * v);
    float e = __expf(2.0f * z);
    return v - v * fast_rcp(e + 1.0f);
}

// XOR swizzle for the radix-16 kfft arrays (strides 1/16/256).
__device__ __forceinline__ int sw(int i) { return (i & ~15) | ((i ^ (i >> 4)) & 15); }
// Swizzle for the 2048 conv array (strides 1/4/32/256): XOR bits 4-7 into low 4.
__device__ __forceinline__ int sw2(int i) { return i ^ ((i >> 4) & 15); }
// Natural bin -> slot for the 8*8*8*4 DIF chain (digit order reversal).
__device__ __forceinline__ int slot2048(int k) {
    return ((k & 7) << 8) | (((k >> 3) & 7) << 5) | (((k >> 6) & 7) << 2) | (k >> 9);
}
// Arithmetic 4-bit reversal (BR4 without the table).
__device__ __forceinline__ int rev4(int x) {
    return ((x & 1) << 3) | ((x & 2) << 1) | ((x & 4) >> 1) | ((x & 8) >> 3);
}

static __device__ const float W16R[8] = {1.f, 0.9238795325f, 0.7071067812f, 0.3826834324f,
                                         0.f, -0.3826834324f, -0.7071067812f, -0.9238795325f};
static __device__ const float W16I[8] = {0.f, -0.3826834324f, -0.7071067812f, -0.9238795325f,
                                         -1.f, -0.9238795325f, -0.7071067812f, -0.3826834324f};
static __device__ const int BR4[16] = {0, 8, 4, 12, 2, 10, 6, 14, 1, 9, 5, 13, 3, 11, 7, 15};
static __device__ const int BR3[8] = {0, 4, 2, 6, 1, 5, 3, 7};

__device__ __forceinline__ float2 twget(const float2* __restrict__ tw, int e) {
    float2 w = tw[e & 2047];
    if (e & 2048) { w.x = -w.x; w.y = -w.y; }
    return w;
}

// ---- radix-8/4 butterfly helpers (fwd: W^k, inv: conj) ----
#define RC8 0.70710678118654752f
template <bool INV>
__device__ __forceinline__ float2 rotI(float2 z) {  // * -i (fwd) / * +i (inv)
    return INV ? make_float2(-z.y, z.x) : make_float2(z.y, -z.x);
}
template <bool INV>
__device__ __forceinline__ float2 rotW(float2 z) {  // * W8 (fwd) / * conj(W8) (inv)
    return INV ? make_float2(RC8 * (z.x - z.y), RC8 * (z.x + z.y))
               : make_float2(RC8 * (z.x + z.y), RC8 * (z.y - z.x));
}
template <bool INV>
__device__ __forceinline__ float2 rotW3(float2 z) {  // * W8^3 (fwd) / * conj (inv)
    return INV ? make_float2(-RC8 * (z.x + z.y), RC8 * (z.x - z.y))
               : make_float2(RC8 * (z.y - z.x), -RC8 * (z.x + z.y));
}

template <bool INV>
__device__ __forceinline__ void bfly8(float2 v[8]) {
    float2 a0 = cadd(v[0], v[4]), a1 = cadd(v[1], v[5]);
    float2 a2 = cadd(v[2], v[6]), a3 = cadd(v[3], v[7]);
    float2 b0 = csub(v[0], v[4]), b1 = csub(v[1], v[5]);
    float2 b2 = csub(v[2], v[6]), b3 = csub(v[3], v[7]);
    float2 c1 = rotW<INV>(b1), c2 = rotI<INV>(b2), c3 = rotW3<INV>(b3);
    float2 e0 = cadd(a0, a2), e1 = csub(a0, a2);
    float2 e2 = cadd(a1, a3), e3 = rotI<INV>(csub(a1, a3));
    v[0] = cadd(e0, e2); v[4] = csub(e0, e2);
    v[2] = cadd(e1, e3); v[6] = csub(e1, e3);
    float2 o0 = cadd(b0, c2), o1 = csub(b0, c2);
    float2 o2 = cadd(c1, c3), o3 = rotI<INV>(csub(c1, c3));
    v[1] = cadd(o0, o2); v[5] = csub(o0, o2);
    v[3] = cadd(o1, o3); v[7] = csub(o1, o3);
}

// Pruned forward butterfly: inputs v[4..7] == 0 (zero-padded upper half).
__device__ __forceinline__ void bfly8_hz(float2 v[8]) {
    float2 x0 = v[0], x1 = v[1], x2 = v[2], x3 = v[3];
    float2 c1 = rotW<false>(x1), c2 = rotI<false>(x2), c3 = rotW3<false>(x3);
    float2 e0 = cadd(x0, x2), e1 = csub(x0, x2);
    float2 e2 = cadd(x1, x3), e3 = rotI<false>(csub(x1, x3));
    v[0] = cadd(e0, e2); v[4] = csub(e0, e2);
    v[2] = cadd(e1, e3); v[6] = csub(e1, e3);
    float2 o0 = cadd(x0, c2), o1 = csub(x0, c2);
    float2 o2 = cadd(c1, c3), o3 = rotI<false>(csub(c1, c3));
    v[1] = cadd(o0, o2); v[5] = csub(o0, o2);
    v[3] = cadd(o1, o3); v[7] = csub(o1, o3);
}

template <bool INV>
__device__ __forceinline__ void bfly4(float2 v[4]) {
    float2 t0 = cadd(v[0], v[2]), t1 = csub(v[0], v[2]);
    float2 t2 = cadd(v[1], v[3]), t3 = csub(v[1], v[3]);
    float2 r3 = rotI<INV>(t3);
    v[0] = cadd(t0, t2); v[2] = csub(t0, t2);
    v[1] = cadd(t1, r3); v[3] = csub(t1, r3);
}

template <bool INV>
__device__ __forceinline__ void fft16_dif(float2 v[16]) {
#pragma unroll
    for (int mi = 0; mi < 4; mi++) {
        const int m = 8 >> mi;
#pragma unroll
        for (int g = 0; g < 16; g += 2 * m) {
#pragma unroll
            for (int j = 0; j < m; j++) {
                float wr = W16R[j << mi];
                float wi = INV ? -W16I[j << mi] : W16I[j << mi];
                float2 a = v[g + j], b = v[g + j + m];
                float dx = a.x - b.x, dy = a.y - b.y;
                v[g + j] = make_float2(a.x + b.x, a.y + b.y);
                v[g + j + m] = make_float2(dx * wr - dy * wi, dx * wi + dy * wr);
            }
        }
    }
}

template <bool INV>
__device__ __forceinline__ void fft8_dif(float2 v[8]) {
#pragma unroll
    for (int mi = 0; mi < 3; mi++) {
        const int m = 4 >> mi;
#pragma unroll
        for (int g = 0; g < 8; g += 2 * m) {
#pragma unroll
            for (int j = 0; j < m; j++) {
                float wr = W16R[j << (mi + 1)];
                float wi = INV ? -W16I[j << (mi + 1)] : W16I[j << (mi + 1)];
                float2 a = v[g + j], b = v[g + j + m];
                float dx = a.x - b.x, dy = a.y - b.y;
                v[g + j] = make_float2(a.x + b.x, a.y + b.y);
                v[g + j + m] = make_float2(dx * wr - dy * wi, dx * wi + dy * wr);
            }
        }
    }
}

// Pass A of the zero-padded (upper half) forward 4096 FFT, input in registers.
__device__ __forceinline__ void fft4096_passA_hz(float2* data, const float2* __restrict__ tw,
                                                 int t, const float2 vin[8]) {
    float2 v[16];
#pragma unroll
    for (int j = 0; j < 8; j++) v[j] = vin[j];
#pragma unroll
    for (int j = 0; j < 8; j++)
        v[j + 8] = cmulf(v[j], make_float2(W16R[j], W16I[j]));
#pragma unroll
    for (int mi = 1; mi < 4; mi++) {
        const int m = 8 >> mi;
#pragma unroll
        for (int g = 0; g < 16; g += 2 * m) {
#pragma unroll
            for (int j = 0; j < m; j++) {
                float wr = W16R[j << mi], wi = W16I[j << mi];
                float2 a = v[g + j], b = v[g + j + m];
                float dx = a.x - b.x, dy = a.y - b.y;
                v[g + j] = make_float2(a.x + b.x, a.y + b.y);
                v[g + j + m] = make_float2(dx * wr - dy * wi, dx * wi + dy * wr);
            }
        }
    }
#pragma unroll
    for (int i = 1; i < 16; i++) v[i] = cmulf(v[i], twget(tw, t * BR4[i]));
#pragma unroll
    for (int i = 0; i < 16; i++) data[sw(i * 256 + t)] = v[i];
}

// Passes B and C of the forward 4096 FFT (leading barrier included).
__device__ __forceinline__ void fft4096_fwd_BC(float2* data, const float2* __restrict__ tw, int t) {
    __syncthreads();
    {
        int j0 = t & 15;
        int base = (t >> 4) * 256 + j0;
        float2 v[16];
#pragma unroll
        for (int k = 0; k < 16; k++) v[k] = data[sw(base + 16 * k)];
        fft16_dif<false>(v);
#pragma unroll
        for (int i = 1; i < 16; i++) v[i] = cmulf(v[i], twget(tw, 16 * j0 * BR4[i]));
#pragma unroll
        for (int i = 0; i < 16; i++) data[sw(base + 16 * i)] = v[i];
    }
    __syncthreads();
    {
        float2 v[16];
#pragma unroll
        for (int k = 0; k < 16; k++) v[k] = data[sw(t * 16 + k)];
        fft16_dif<false>(v);
#pragma unroll
        for (int i = 0; i < 16; i++) data[sw(t * 16 + i)] = v[i];
    }
    __syncthreads();
}

// ---------------- kfft core: spectrum -> ifft2048 -> rfft4096 -> Kd (one (layer,h)) ----
// Kd written in NATURAL bin order: Kd[k] = X_k read from slot
// 256*rev4(k&15) + 16*rev4((k>>4)&15) + rev4(k>>8) (R24-verified mapping,
// arithmetic bitrev). smem = 10240 floats (40KB), pole/ktmp overlay as R25.
__device__ __forceinline__ void kfft_core(int hh, int t, float* smem,
                                          float2* __restrict__ KdL,
                                          const float2* __restrict__ tw,
                                          const float* __restrict__ lam_re,
                                          const float* __restrict__ lam_im,
                                          const float* __restrict__ p_re,
                                          const float* __restrict__ p_im,
                                          const float* __restrict__ b_re,
                                          const float* __restrict__ b_im,
                                          const float* __restrict__ c_re,
                                          const float* __restrict__ c_im,
                                          const float* __restrict__ log_step) {
    float2* data = (float2*)smem;            // floats [0,8192)
    float4* polA = (float4*)(smem + 8192);   // dead after Cauchy
    float4* polB = (float4*)(smem + 8448);
    float* n11S = smem + 8704;
    float* ktmp = smem + 8192;               // born after fft8
    int baseP = hh * Npol;
    if (t < Npol) {
        int n = t;
        float lr = lam_re[baseP + n], li = lam_im[baseP + n];
        float pr = p_re[baseP + n], pi = p_im[baseP + n];
        float br = b_re[baseP + n], bi = b_im[baseP + n];
        float cr = c_re[baseP + n], ci = c_im[baseP + n];
        polA[n] = make_float4(lr, li, cr * br + ci * bi, cr * bi - ci * br);
        polB[n] = make_float4(cr * pr + ci * pi, cr * pi - ci * pr,
                              pr * br + pi * bi, pr * bi - pi * br);
        n11S[n] = pr * pr + pi * pi;
    }
    __syncthreads();
    {   // ---- Cauchy spectrum: 8 l-positions per thread, into data[sw(l)] ----
        float step = expf(log_step[hh]);
        float gs = 2.0f / step;
        float wrv[8], wiv[8];
        float gr[8], gi[8];
#pragma unroll
        for (int j = 0; j < 8; j++) {
            int l = t + 256 * j;
            float ang = -6.283185307179586f * (float)l / (float)Lseq;
            float wr = cosf(ang), wi = sinf(ang);  // fp32 trig on purpose (see header)
            wrv[j] = wr; wiv[j] = wi;
            float dr = 1.0f + wr, di = wi;
            float invd2 = fast_rcp(dr * dr + di * di);
            float nr = 1.0f - wr, ni = -wi;
            gr[j] = gs * (nr * dr + ni * di) * invd2;
            gi[j] = gs * (ni * dr - nr * di) * invd2;
        }
        float k00x[8], k00y[8], k01x[8], k01y[8];
        float k10x[8], k10y[8], k11x[8], k11y[8];
#pragma unroll
        for (int j = 0; j < 8; j++) {
            k00x[j] = 0.f; k00y[j] = 0.f; k01x[j] = 0.f; k01y[j] = 0.f;
            k10x[j] = 0.f; k10y[j] = 0.f; k11x[j] = 0.f; k11y[j] = 0.f;
        }
        for (int n = 0; n < Npol; n++) {
            float4 A = polA[n];
            float4 B = polB[n];
            float n11 = n11S[n];
#pragma unroll
            for (int j = 0; j < 8; j++) {
                float er = gr[j] - A.x, ei = gi[j] - A.y;
                float inv2 = fast_rcp(fmaf(er, er, ei * ei));
                float ir = er * inv2;
                float mi = ei * inv2;
                k00x[j] = fmaf(A.z, ir, fmaf(A.w, mi, k00x[j]));
                k00y[j] = fmaf(A.w, ir, fmaf(-A.z, mi, k00y[j]));
                k01x[j] = fmaf(B.x, ir, fmaf(B.y, mi, k01x[j]));
                k01y[j] = fmaf(B.y, ir, fmaf(-B.x, mi, k01y[j]));
                k10x[j] = fmaf(B.z, ir, fmaf(B.w, mi, k10x[j]));
                k10y[j] = fmaf(B.w, ir, fmaf(-B.z, mi, k10y[j]));
                k11x[j] = fmaf(n11, ir, k11x[j]);
                k11y[j] = fmaf(-n11, mi, k11y[j]);
            }
        }
#pragma unroll
        for (int j = 0; j < 8; j++) {
            int l = t + 256 * j;
            float dr = 1.0f + wrv[j], di = wiv[j];
            float invd2 = fast_rcp(dr * dr + di * di);
            float cr2 = 2.0f * dr * invd2, ci2 = -2.0f * di * invd2;
            float wr2 = 1.0f + k11x[j], wi2 = k11y[j];
            float w2inv = fast_rcp(fmaf(wr2, wr2, wi2 * wi2));
            float vr = wr2 * w2inv, vi = -wi2 * w2inv;
            float t1x = k01x[j] * k10x[j] - k01y[j] * k10y[j];
            float t1y = k01x[j] * k10y[j] + k01y[j] * k10x[j];
            float t2x = t1x * vr - t1y * vi, t2y = t1x * vi + t1y * vr;
            float ex = k00x[j] - t2x, ey = k00y[j] - t2y;
            data[sw(l)] = make_float2(cr2 * ex - ci2 * ey, cr2 * ey + ci2 * ex);
        }
    }
    __syncthreads();
    if (t < 128) {
        float2 v[16];
#pragma unroll
        for (int k = 0; k < 16; k++) v[k] = data[sw(t + 128 * k)];
        fft16_dif<true>(v);
#pragma unroll
        for (int i = 1; i < 16; i++) v[i] = cmulc(v[i], twget(tw, 2 * t * BR4[i]));
#pragma unroll
        for (int i = 0; i < 16; i++) data[sw(i * 128 + t)] = v[i];
    }
    __syncthreads();
    if (t < 128) {
        int i2 = t >> 3, j0 = t & 7;
        int base2 = i2 * 128 + j0;
        float2 v[16];
#pragma unroll
        for (int k = 0; k < 16; k++) v[k] = data[sw(base2 + 8 * k)];
        fft16_dif<true>(v);
#pragma unroll
        for (int i = 1; i < 16; i++) v[i] = cmulc(v[i], twget(tw, 32 * j0 * BR4[i]));
#pragma unroll
        for (int i = 0; i < 16; i++) data[sw(base2 + 8 * i)] = v[i];
    }
    __syncthreads();
    {
        float2 v8[8];
#pragma unroll
        for (int k = 0; k < 8; k++) v8[k] = data[sw(t * 8 + k)];
        fft8_dif<true>(v8);
        int r = BR4[t >> 4], s = BR4[t & 15];
#pragma unroll
        for (int i = 0; i < 8; i++) {
            int l = r + 16 * s + 256 * BR3[i];
            ktmp[l] = v8[i].x * (1.0f / 2048.0f);
        }
    }
    __syncthreads();
    {
        float2 vin[8];
#pragma unroll
        for (int k = 0; k < 8; k++) vin[k] = make_float2(ktmp[t + 256 * k], 0.f);
        fft4096_passA_hz(data, tw, t, vin);
    }
    fft4096_fwd_BC(data, tw, t);
    float2* dst = KdL + (size_t)hh * 4096;
#pragma unroll
    for (int k = 0; k < 16; k++) {
        int p = t + 256 * k;  // natural bin index
        int q = (rev4(p & 15) << 8) | (rev4((p >> 4) & 15) << 4) | rev4(p >> 8);
        dst[p] = data[sw(q)];
    }
}

// ---------------- prep: twiddle + bf16 weights (w1,w2,dec_w,enc_w) ----------------
__global__ __launch_bounds__(256, 4) void prep_kernel(const float* __restrict__ w1,
                                                      const float* __restrict__ w2,
                                                      const float* __restrict__ dec_w,
                                                      const float* __restrict__ enc_w,
                                                      float2* __restrict__ tw,
                                                      __bf16* __restrict__ wbf,
                                                      __bf16* __restrict__ decbf,
                                                      __bf16* __restrict__ encbf) {
    int bid = blockIdx.x, t = threadIdx.x;
    if (bid < 8) {
        int k = bid * 256 + t;
        if (k < 2048) {
            double a = -6.283185307179586476925286766559 * (double)k / 4096.0;
            tw[k] = make_float2((float)cos(a), (float)sin(a));
        }
        return;
    }
    if (bid < 264) {
        int i = (bid - 8) * 256 + t;
        int layer = i >> 14, rem = i & 16383;
        wbf[((size_t)layer * 2) * 16384 + rem] = (__bf16)w1[i];
        wbf[((size_t)layer * 2 + 1) * 16384 + rem] = (__bf16)w2[i];
        return;
    }
    if (bid < 296) {  // dec_w (64x128) -> bf16
        int i = (bid - 264) * 256 + t;
        decbf[i] = (__bf16)dec_w[i];
        return;
    }
    // enc_w (128x64) -> bf16
    int i = (bid - 296) * 256 + t;
    encbf[i] = (__bf16)enc_w[i];
}

// ---------------- kfft (all layers) + MFMA encoder merged ----------------
__global__ __launch_bounds__(256) void kfft_enc_kernel(float2* __restrict__ Kd1,
                                                       const float2* __restrict__ tw,
                                                       const float* __restrict__ x,
                                                       const __bf16* __restrict__ encbf,
                                                       const float* __restrict__ enc_b,
                                                       const float* __restrict__ nw,
                                                       const float* __restrict__ nb,
                                                       float* __restrict__ h,
                                                       float* __restrict__ hnT,
                                                       const float* __restrict__ lam_re,
                                                       const float* __restrict__ lam_im,
                                                       const float* __restrict__ p_re,
                                                       const float* __restrict__ p_im,
                                                       const float* __restrict__ b_re,
                                                       const float* __restrict__ b_im,
                                                       const float* __restrict__ c_re,
                                                       const float* __restrict__ c_im,
                                                       const float* __restrict__ log_step) {
    __shared__ __align__(16) float smem[10240];
    int bid = blockIdx.x, t = threadIdx.x;
    if (bid < 512) {
        int hh = bid & 127, layer = bid >> 7;
        int PN = Hdim * Npol;
        kfft_core(hh, t, smem, Kd1 + (size_t)layer * Hdim * 4096, tw,
                  lam_re + layer * PN, lam_im + layer * PN,
                  p_re + layer * PN, p_im + layer * PN,
                  b_re + layer * PN, b_im + layer * PN,
                  c_re + layer * PN, c_im + layer * PN,
                  log_step + layer * Hdim);
    } else {
        // ---- encoder via bf16 MFMA + fused LN: 32 rows/block ----
        int r0 = (bid - 512) * 32;
        __bf16* ybf = (__bf16*)smem;              // 32*72 bf16
        float* dots = smem + 1152;                // 32*132 floats
        float2* mv = (float2*)(smem + 5376);      // 32 float2
        int bb = r0 >> 11, l0 = r0 & 2047;
        for (int i = t; i < 32 * 64; i += 256) {
            int r = i >> 6, k = i & 63;
            ybf[r * 72 + k] = (__bf16)x[(size_t)(r0 + r) * 64 + k];
        }
        __syncthreads();
        int wave = t >> 6, lane = t & 63;
        int m = lane & 31, half = lane >> 5;
        bf16x8 a[4];
#pragma unroll
        for (int kk = 0; kk < 4; kk++)
            a[kk] = *(const bf16x8*)&ybf[m * 72 + kk * 16 + half * 8];
        int o = 32 * wave + m;
        const __bf16* wr = encbf + (size_t)o * 64 + half * 8;
        f32x16 acc;
#pragma unroll
        for (int i = 0; i < 16; i++) acc[i] = 0.f;
#pragma unroll
        for (int kk = 0; kk < 4; kk++) {
            bf16x8 bw = *(const bf16x8*)(wr + kk * 16);
            acc = __builtin_amdgcn_mfma_f32_32x32x16_bf16(a[kk], bw, acc, 0, 0, 0);
        }
        float bo = enc_b[o];
#pragma unroll
        for (int reg = 0; reg < 16; reg++) {
            int row = (reg & 3) + 8 * (reg >> 2) + 4 * half;
            dots[row * 132 + o] = acc[reg] + bo;
        }
        __syncthreads();
        {
            int row = t >> 3, lane8 = t & 7;
            float s1 = 0.f, s2 = 0.f;
            int base = row * 132 + lane8 * 16;
#pragma unroll
            for (int q = 0; q < 4; q++) {
                float4 v4 = *(const float4*)&dots[base + 4 * q];
                s1 += v4.x + v4.y + v4.z + v4.w;
                s2 += v4.x * v4.x + v4.y * v4.y + v4.z * v4.z + v4.w * v4.w;
            }
#pragma unroll
            for (int mm = 1; mm < 8; mm <<= 1) { s1 += __shfl_xor(s1, mm); s2 += __shfl_xor(s2, mm); }
            if (lane8 == 0) {
                float mu = s1 * (1.0f / 128.0f);
                float var = s2 * (1.0f / 128.0f) - mu * mu;
                mv[row] = make_float2(mu, fast_rsq(var + 1e-5f));
            }
        }
        __syncthreads();
        {
            int o2 = t & 127, rh = t >> 7;
            float nwc = nw[o2], nbc = nb[o2];
            float hnv[16];
#pragma unroll
            for (int j = 0; j < 16; j++) {
                int r = rh * 16 + j;
                float hvv = dots[r * 132 + o2];
                h[(size_t)(r0 + r) * Hdim + o2] = hvv;
                float2 mvv = mv[r];
                hnv[j] = (hvv - mvv.x) * mvv.y * nwc + nbc;
            }
            float* dst = hnT + ((size_t)bb * Hdim + o2) * Lseq + l0 + rh * 16;
            *(float4*)(dst)      = make_float4(hnv[0],  hnv[1],  hnv[2],  hnv[3]);
            *(float4*)(dst + 4)  = make_float4(hnv[4],  hnv[5],  hnv[6],  hnv[7]);
            *(float4*)(dst + 8)  = make_float4(hnv[8],  hnv[9],  hnv[10], hnv[11]);
            *(float4*)(dst + 12) = make_float4(hnv[12], hnv[13], hnv[14], hnv[15]);
        }
    }
}

// ---- Hermitian pair pointwise: given bins k (<1024) and kp=(2048-k)&2047,
// form U from Z, multiply by Kd, repack E+iO (incl. 1/2048 inverse scale). ----
__device__ __forceinline__ void pw_pair(float2* data, const float2* __restrict__ tw,
                                        int k, float2 Kdk, float2 Kdk2) {
    const float s = 1.0f / 2048.0f;
    int kp = (2048 - k) & 2047;
    int s1 = sw2(slot2048(k));
    int s2 = sw2(slot2048(kp));
    float2 Zk = data[s1], Zp = data[s2];
    float2 A = make_float2(0.5f * (Zk.x + Zp.x), 0.5f * (Zk.y - Zp.y));
    float2 Bv = make_float2(0.5f * (Zk.y + Zp.y), 0.5f * (Zp.x - Zk.x));
    float2 W = twget(tw, k);                 // exp(-2*pi*i*k/4096)
    float2 WB = cmulf(W, Bv);
    float2 Up = cadd(A, WB);                 // U_k
    float2 Um = csub(A, WB);                 // U_{k+2048}
    float2 Vp = cmulf(Up, Kdk);
    float2 Vm = cmulf(Um, Kdk2);
    float2 E = make_float2(0.5f * (Vp.x + Vm.x), 0.5f * (Vp.y + Vm.y));
    float2 Dv = make_float2(0.5f * (Vp.x - Vm.x), 0.5f * (Vp.y - Vm.y));
    float2 O = cmulc(Dv, W);                 // exp(+2*pi*i*k/4096) * Dv
    data[s1] = make_float2(s * (E.x - O.y), s * (E.y + O.x));
    if (s2 != s1)
        data[s2] = make_float2(s * (E.x + O.y), s * (O.x - E.y));
}

// ---------------- FFT convolution: per-(h,batch) real conv via 2048-pt FFT --------
// z_n = u_{2n} + i*u_{2n+1} (n<1024 nonzero). Fwd 8*8*8*4 DIF, Hermitian pair
// phase with natural-order Kd, inverse chain, unpack y from Re/Im. 1024 blocks.
__global__ __launch_bounds__(256) void conv_kernel(float* __restrict__ hnT,
                                                   const float2* __restrict__ Kd1,
                                                   const float* __restrict__ dvec,
                                                   const float2* __restrict__ tw) {
    int h = blockIdx.x, b = blockIdx.y, t = threadIdx.x;
    __shared__ float2 data[2048];
    float* u0 = hnT + ((size_t)b * Hdim + h) * Lseq;
    float2 ureg[4];
    float2 Kreg[8];
    float2 Knyq0, Knyq1;
    const float2* Kp = Kd1 + (size_t)h * 4096;
    {   // P1: load z (pruned: upper half zero) + Kd prefetch; radix-8, stride 256
        float2 v[8];
        const float2* up = (const float2*)u0;
#pragma unroll
        for (int r = 0; r < 4; r++) {
            float2 z = up[t + 256 * r];
            ureg[r] = z;
            v[r] = z;
        }
#pragma unroll
        for (int j = 0; j < 4; j++) {
            Kreg[2 * j] = Kp[t + 256 * j];
            Kreg[2 * j + 1] = Kp[t + 256 * j + 2048];
        }
        if (t == 0) { Knyq0 = Kp[1024]; Knyq1 = Kp[3072]; }
        bfly8_hz(v);
#pragma unroll
        for (int m = 1; m < 8; m++) v[m] = cmulf(v[m], twget(tw, 2 * t * m));
#pragma unroll
        for (int m = 0; m < 8; m++) data[sw2(m * 256 + t)] = v[m];
    }
    __syncthreads();
    {   // P2: radix-8 within 256-blocks, stride 32
        int g = t >> 5, u5 = t & 31;
        int base = g * 256 + u5;
        float2 v[8];
#pragma unroll
        for (int r = 0; r < 8; r++) v[r] = data[sw2(base + 32 * r)];
        bfly8<false>(v);
#pragma unroll
        for (int m = 1; m < 8; m++) v[m] = cmulf(v[m], twget(tw, 16 * u5 * m));
#pragma unroll
        for (int m = 0; m < 8; m++) data[sw2(g * 256 + m * 32 + u5)] = v[m];
    }
    __syncthreads();
    {   // P3: radix-8 within 32-blocks, stride 4
        int c = t >> 2, q = t & 3;
        int base = c * 32 + q;
        float2 v[8];
#pragma unroll
        for (int r = 0; r < 8; r++) v[r] = data[sw2(base + 4 * r)];
        bfly8<false>(v);
#pragma unroll
        for (int m = 1; m < 8; m++) v[m] = cmulf(v[m], twget(tw, 128 * q * m));
#pragma unroll
        for (int m = 0; m < 8; m++) data[sw2(c * 32 + m * 4 + q)] = v[m];
    }
    __syncthreads();
    {   // P4: radix-4 within 4-blocks (no twiddle), 2 butterflies/thread
#pragma unroll
        for (int e = 0; e < 2; e++) {
            int bidx = t + 256 * e;
            float2 v[4];
#pragma unroll
            for (int d = 0; d < 4; d++) v[d] = data[sw2(4 * bidx + d)];
            bfly4<false>(v);
#pragma unroll
            for (int d = 0; d < 4; d++) data[sw2(4 * bidx + d)] = v[d];
        }
    }
    __syncthreads();
    {   // P5: Hermitian pair pointwise in bin space
#pragma unroll
        for (int j = 0; j < 4; j++)
            pw_pair(data, tw, t + 256 * j, Kreg[2 * j], Kreg[2 * j + 1]);
        if (t == 0) pw_pair(data, tw, 1024, Knyq0, Knyq1);
    }
    __syncthreads();
    {   // P6: inverse radix-4
#pragma unroll
        for (int e = 0; e < 2; e++) {
            int bidx = t + 256 * e;
            float2 v[4];
#pragma unroll
            for (int d = 0; d < 4; d++) v[d] = data[sw2(4 * bidx + d)];
            bfly4<true>(v);
#pragma unroll
            for (int d = 0; d < 4; d++) data[sw2(4 * bidx + d)] = v[d];
        }
    }
    __syncthreads();
    {   // P7: inverse of P3
        int c = t >> 2, q = t & 3;
        float2 v[8];
#pragma unroll
        for (int m = 0; m < 8; m++) v[m] = data[sw2(c * 32 + m * 4 + q)];
#pragma unroll
        for (int m = 1; m < 8; m++) v[m] = cmulc(v[m], twget(tw, 128 * q * m));
        bfly8<true>(v);
#pragma unroll
        for (int r = 0; r < 8; r++) data[sw2(c * 32 + q + 4 * r)] = v[r];
    }
    __syncthreads();
    {   // P8: inverse of P2
        int g = t >> 5, u5 = t & 31;
        float2 v[8];
#pragma unroll
        for (int m = 0; m < 8; m++) v[m] = data[sw2(g * 256 + m * 32 + u5)];
#pragma unroll
        for (int m = 1; m < 8; m++) v[m] = cmulc(v[m], twget(tw, 16 * u5 * m));
        bfly8<true>(v);
#pragma unroll
        for (int r = 0; r < 8; r++) data[sw2(g * 256 + u5 + 32 * r)] = v[r];
    }
    __syncthreads();
    {   // P9: inverse of P1; keep n<1024 outputs; unpack + D-term + gelu
        float2 v[8];
#pragma unroll
        for (int m = 0; m < 8; m++) v[m] = data[sw2(m * 256 + t)];
#pragma unroll
        for (int m = 1; m < 8; m++) v[m] = cmulc(v[m], twget(tw, 2 * t * m));
        bfly8<true>(v);
        float dcoef = dvec[h];
        float2* up = (float2*)u0;
#pragma unroll
        for (int r = 0; r < 4; r++) {
            float2 w = v[r];
            float2 uo = ureg[r];
            up[t + 256 * r] = make_float2(gelu_f(w.x + uo.x * dcoef),
                                          gelu_f(w.y + uo.y * dcoef));
        }
    }
}

// ---------------- gated MLP via bf16 MFMA + residual + fused LN: 32 rows/block ----------------
__global__ __launch_bounds__(256) void mlp_kernel(const float* __restrict__ yT,
                                                  float* __restrict__ h,
                                                  float* __restrict__ hnT,
                                                  const __bf16* __restrict__ w1b,
                                                  const __bf16* __restrict__ w2b,
                                                  const float* __restrict__ b1,
                                                  const float* __restrict__ b2,
                                                  const float* __restrict__ nw,
                                                  const float* __restrict__ nb) {
    int r0 = blockIdx.x * 32;
    int t = threadIdx.x;
    int wave = t >> 6, lane = t & 63;
    __shared__ __align__(16) __bf16 ybf[32 * 136];
    __shared__ float dots[32 * 132];
    __shared__ float2 mv[32];
    int bb = r0 >> 11, l0 = r0 & 2047;
    for (int i = t; i < 32 * 128; i += 256) {
        int r = i & 31, k = i >> 5;
        ybf[r * 136 + k] = (__bf16)yT[((size_t)bb * Hdim + k) * Lseq + l0 + r];
    }
    __syncthreads();
    int m = lane & 31, half = lane >> 5;
    bf16x8 a[8];
#pragma unroll
    for (int kk = 0; kk < 8; kk++)
        a[kk] = *(const bf16x8*)&ybf[m * 136 + kk * 16 + half * 8];
    int out = 32 * wave + m;
    const __bf16* w1r = w1b + (size_t)out * 128 + half * 8;
    const __bf16* w2r = w2b + (size_t)out * 128 + half * 8;
    f32x16 acc1, acc2;
#pragma unroll
    for (int i = 0; i < 16; i++) { acc1[i] = 0.f; acc2[i] = 0.f; }
#pragma unroll
    for (int kk = 0; kk < 8; kk++) {
        bf16x8 bw1 = *(const bf16x8*)(w1r + kk * 16);
        bf16x8 bw2 = *(const bf16x8*)(w2r + kk * 16);
        acc1 = __builtin_amdgcn_mfma_f32_32x32x16_bf16(a[kk], bw1, acc1, 0, 0, 0);
        acc2 = __builtin_amdgcn_mfma_f32_32x32x16_bf16(a[kk], bw2, acc2, 0, 0, 0);
    }
    float bias1 = b1[out], bias2 = b2[out];
#pragma unroll
    for (int reg = 0; reg < 16; reg++) {
        int row = (reg & 3) + 8 * (reg >> 2) + 4 * half;
        float v1 = acc1[reg] + bias1;
        float v2 = acc2[reg] + bias2;
        float g = fast_rcp(1.0f + __expf(-v2));
        float hv = h[(size_t)(r0 + row) * Hdim + out] + v1 * g;
        dots[row * 132 + out] = hv;
    }
    __syncthreads();
    {
        int row = t >> 3, lane8 = t & 7;
        float s1 = 0.f, s2 = 0.f;
        int base = row * 132 + lane8 * 16;
#pragma unroll
        for (int q = 0; q < 4; q++) {
            float4 v4 = *(const float4*)&dots[base + 4 * q];
            s1 += v4.x + v4.y + v4.z + v4.w;
            s2 += v4.x * v4.x + v4.y * v4.y + v4.z * v4.z + v4.w * v4.w;
        }
#pragma unroll
        for (int mm = 1; mm < 8; mm <<= 1) { s1 += __shfl_xor(s1, mm); s2 += __shfl_xor(s2, mm); }
        if (lane8 == 0) {
            float mu = s1 * (1.0f / 128.0f);
            float var = s2 * (1.0f / 128.0f) - mu * mu;
            mv[row] = make_float2(mu, fast_rsq(var + 1e-5f));
        }
    }
    __syncthreads();
    {
        int o = t & 127, rh = t >> 7;
        float nwc = nw[o], nbc = nb[o];
        float hnv[16];
#pragma unroll
        for (int j = 0; j < 16; j++) {
            int r = rh * 16 + j;
            float hvv = dots[r * 132 + o];
            h[(size_t)(r0 + r) * Hdim + o] = hvv;
            float2 mvv = mv[r];
            hnv[j] = (hvv - mvv.x) * mvv.y * nwc + nbc;
        }
        float* dst = hnT + ((size_t)bb * Hdim + o) * Lseq + l0 + rh * 16;
        *(float4*)(dst)      = make_float4(hnv[0],  hnv[1],  hnv[2],  hnv[3]);
        *(float4*)(dst + 4)  = make_float4(hnv[4],  hnv[5],  hnv[6],  hnv[7]);
        *(float4*)(dst + 8)  = make_float4(hnv[8],  hnv[9],  hnv[10], hnv[11]);
        *(float4*)(dst + 12) = make_float4(hnv[12], hnv[13], hnv[14], hnv[15]);
    }
}

// ---------------- last layer: gated MLP + residual + fused DECODER (bf16 MFMA) ----------
__global__ __launch_bounds__(256) void mlpdec_kernel(const float* __restrict__ yT,
                                                     const float* __restrict__ h,
                                                     const __bf16* __restrict__ w1b,
                                                     const __bf16* __restrict__ w2b,
                                                     const float* __restrict__ b1,
                                                     const float* __restrict__ b2,
                                                     const __bf16* __restrict__ decb,
                                                     const float* __restrict__ dec_bias,
                                                     float* __restrict__ out) {
    int r0 = blockIdx.x * 32;
    int t = threadIdx.x;
    int wave = t >> 6, lane = t & 63;
    __shared__ __align__(16) __bf16 ybf[32 * 136];
    __shared__ float dots[32 * 132];
    int bb = r0 >> 11, l0 = r0 & 2047;
    for (int i = t; i < 32 * 128; i += 256) {
        int r = i & 31, k = i >> 5;
        ybf[r * 136 + k] = (__bf16)yT[((size_t)bb * Hdim + k) * Lseq + l0 + r];
    }
    __syncthreads();
    int m = lane & 31, half = lane >> 5;
    bf16x8 a[8];
#pragma unroll
    for (int kk = 0; kk < 8; kk++)
        a[kk] = *(const bf16x8*)&ybf[m * 136 + kk * 16 + half * 8];
    int outc = 32 * wave + m;
    const __bf16* w1r = w1b + (size_t)outc * 128 + half * 8;
    const __bf16* w2r = w2b + (size_t)outc * 128 + half * 8;
    f32x16 acc1, acc2;
#pragma unroll
    for (int i = 0; i < 16; i++) { acc1[i] = 0.f; acc2[i] = 0.f; }
#pragma unroll
    for (int kk = 0; kk < 8; kk++) {
        bf16x8 bw1 = *(const bf16x8*)(w1r + kk * 16);
        bf16x8 bw2 = *(const bf16x8*)(w2r + kk * 16);
        acc1 = __builtin_amdgcn_mfma_f32_32x32x16_bf16(a[kk], bw1, acc1, 0, 0, 0);
        acc2 = __builtin_amdgcn_mfma_f32_32x32x16_bf16(a[kk], bw2, acc2, 0, 0, 0);
    }
    float bias1 = b1[outc], bias2 = b2[outc];
#pragma unroll
    for (int reg = 0; reg < 16; reg++) {
        int row = (reg & 3) + 8 * (reg >> 2) + 4 * half;
        float v1 = acc1[reg] + bias1;
        float v2 = acc2[reg] + bias2;
        float g = fast_rcp(1.0f + __expf(-v2));
        float hv = h[(size_t)(r0 + row) * Hdim + outc] + v1 * g;
        dots[row * 132 + outc] = hv;
    }
    __syncthreads();
    // restage h tile as bf16 A-operands
    for (int i = t; i < 32 * 128; i += 256) {
        int r = i >> 7, k = i & 127;
        ybf[r * 136 + k] = (__bf16)dots[r * 132 + k];
    }
    __syncthreads();
    if (wave < 2) {  // decoder GEMM: 32 rows x 64 outs, K=128
        bf16x8 a2[8];
#pragma unroll
        for (int kk = 0; kk < 8; kk++)
            a2[kk] = *(const bf16x8*)&ybf[m * 136 + kk * 16 + half * 8];
        int oc = 32 * wave + m;  // 0..63
        const __bf16* wr = decb + (size_t)oc * 128 + half * 8;
        f32x16 acc;
#pragma unroll
        for (int i = 0; i < 16; i++) acc[i] = 0.f;
#pragma unroll
        for (int kk = 0; kk < 8; kk++) {
            bf16x8 bw = *(const bf16x8*)(wr + kk * 16);
            acc = __builtin_amdgcn_mfma_f32_32x32x16_bf16(a2[kk], bw, acc, 0, 0, 0);
        }
        float bo = dec_bias[oc];
#pragma unroll
        for (int reg = 0; reg < 16; reg++) {
            int row = (reg & 3) + 8 * (reg >> 2) + 4 * half;
            out[(size_t)(r0 + row) * 64 + oc] = acc[reg] + bo;
        }
    }
}

extern "C" void kernel_launch(void* const* d_in, const int* in_sizes, int n_in,
                              void* d_out, int out_size, void* d_ws, size_t ws_size,
                              hipStream_t stream) {
    const float* x      = (const float*)d_in[0];
    const float* enc_w  = (const float*)d_in[2];
    const float* enc_b  = (const float*)d_in[3];
    const float* dec_w  = (const float*)d_in[4];
    const float* dec_b  = (const float*)d_in[5];
    const float* lam_re = (const float*)d_in[6];
    const float* lam_im = (const float*)d_in[7];
    const float* p_re   = (const float*)d_in[8];
    const float* p_im   = (const float*)d_in[9];
    const float* b_re   = (const float*)d_in[10];
    const float* b_im   = (const float*)d_in[11];
    const float* c_re   = (const float*)d_in[12];
    const float* c_im   = (const float*)d_in[13];
    const float* dvec   = (const float*)d_in[14];
    const float* lstep  = (const float*)d_in[15];
    const float* norm_w = (const float*)d_in[16];
    const float* norm_b = (const float*)d_in[17];
    const float* w1     = (const float*)d_in[18];
    const float* b1     = (const float*)d_in[19];
    const float* w2     = (const float*)d_in[20];
    const float* b2     = (const float*)d_in[21];
    float* out = (float*)d_out;

    char* ws = (char*)d_ws;
    float2* tw  = (float2*)ws;  ws += 2048 * sizeof(float2);
    float*  h   = (float*)ws;   ws += (size_t)Bsz * Lseq * Hdim * sizeof(float);
    float*  hnT = (float*)ws;   ws += (size_t)Bsz * Lseq * Hdim * sizeof(float);
    float2* Kd1 = (float2*)ws;  ws += (size_t)NLAYERS * Hdim * 4096 * sizeof(float2);
    __bf16* wbf = (__bf16*)ws;  ws += (size_t)NLAYERS * 2 * Hdim * Hdim * sizeof(__bf16);
    __bf16* dbf = (__bf16*)ws;  ws += (size_t)64 * Hdim * sizeof(__bf16);
    __bf16* ebf = (__bf16*)ws;  ws += (size_t)Hdim * 64 * sizeof(__bf16);

    const int nrows = Bsz * Lseq;  // 16384

    prep_kernel<<<328, 256, 0, stream>>>(w1, w2, dec_w, enc_w, tw, wbf, dbf, ebf);
    kfft_enc_kernel<<<512 + nrows / 32, 256, 0, stream>>>(
        Kd1, tw, x, ebf, enc_b, norm_w, norm_b, h, hnT,
        lam_re, lam_im, p_re, p_im, b_re, b_im, c_re, c_im, lstep);
    for (int L = 0; L < NLAYERS; L++) {
        conv_kernel<<<dim3(Hdim, Bsz), 256, 0, stream>>>(
            hnT, Kd1 + (size_t)L * Hdim * 4096, dvec + L * Hdim, tw);
        const __bf16* w1bL = wbf + (size_t)L * 2 * Hdim * Hdim;
        const __bf16* w2bL = w1bL + Hdim * Hdim;
        if (L < NLAYERS - 1) {
            const float* nwn = norm_w + (L + 1) * Hdim;
            const float* nbn = norm_b + (L + 1) * Hdim;
            mlp_kernel<<<nrows / 32, 256, 0, stream>>>(hnT, h, hnT, w1bL, w2bL,
                                                       b1 + L * Hdim, b2 + L * Hdim,
                                                       nwn, nbn);
        } else {
            mlpdec_kernel<<<nrows / 32, 256, 0, stream>>>(hnT, h, w1bL, w2bL,
                                                          b1 + L * Hdim, b2 + L * Hdim,
                                                          dbf, dec_b, out);
        }
    }
}

// Round 11
// 279.339 us; speedup vs baseline: 1.1236x; 1.1236x over previous
//
#include <hip/hip_runtime.h>
#include <hip/hip_bf16.h>

// S4 (DPLR) forward, B=8 L=2048 IN=OUT=64 H=128 N=64, 4 layers.
// R27 = R25 (best known: radix-16 conv, natural Kd, MFMA encoder, kfft LDS
// overlay 40KB = 4 blocks/CU) + XCD-aware conv block remap: 1D grid with
// bid = (h&7) + 8*((h>>3)*4 + bp) puts the 4 same-h blocks (which share a 32KB
// Kd slice) on the SAME XCD under round-robin dispatch -> 3 of 4 Kd reads hit
// that XCD's L2 instead of HBM. Perf heuristic only; math identical to R25.
// R26's half-size-FFT conv reverted (9 phases/8 barriers + scatter pointwise +
// scrambled Kd store: 277.5 -> 313.9, third failed conv restructure).
// omega via cosf/sinf on purpose (l=1024 bilinear singularity, see kfft_core).

#define Bsz 8
#define Lseq 2048
#define Hdim 128
#define Npol 64
#define NLAYERS 4

typedef __bf16 bf16x8 __attribute__((ext_vector_type(8)));
typedef float f32x16 __attribute__((ext_vector_type(16)));

__device__ __forceinline__ float fast_rcp(float x) { return __builtin_amdgcn_rcpf(x); }
__device__ __forceinline__ float fast_rsq(float x) { return __builtin_amdgcn_rsqf(x); }

__device__ __forceinline__ float2 cmulf(float2 a, float2 b) {
    return make_float2(a.x * b.x - a.y * b.y, a.x * b.y + a.y * b.x);
}
__device__ __forceinline__ float2 cmulc(float2 a, float2 b) {  // a * conj(b)
    return make_float2(a.x * b.x + a.y * b.y, a.y * b.x - a.x * b.y);
}

__device__ __forceinline__ float gelu_f(float v) {
    float z = 0.7978845608028654f * (v + 0.044715f * v * v * v);
    float e = __expf(2.0f * z);
    return v - v * fast_rcp(e + 1.0f);
}

// XOR swizzle: strides 1/16/256 all conflict-uniform for the 4096 arrays.
__device__ __forceinline__ int sw(int i) { return (i & ~15) | ((i ^ (i >> 4)) & 15); }

static __device__ const float W16R[8] = {1.f, 0.9238795325f, 0.7071067812f, 0.3826834324f,
                                         0.f, -0.3826834324f, -0.7071067812f, -0.9238795325f};
static __device__ const float W16I[8] = {0.f, -0.3826834324f, -0.7071067812f, -0.9238795325f,
                                         -1.f, -0.9238795325f, -0.7071067812f, -0.3826834324f};
static __device__ const int BR4[16] = {0, 8, 4, 12, 2, 10, 6, 14, 1, 9, 5, 13, 3, 11, 7, 15};
static __device__ const int BR3[8] = {0, 4, 2, 6, 1, 5, 3, 7};

__device__ __forceinline__ float2 twget(const float2* __restrict__ tw, int e) {
    float2 w = tw[e & 2047];
    if (e & 2048) { w.x = -w.x; w.y = -w.y; }
    return w;
}

template <bool INV>
__device__ __forceinline__ void fft16_dif(float2 v[16]) {
#pragma unroll
    for (int mi = 0; mi < 4; mi++) {
        const int m = 8 >> mi;
#pragma unroll
        for (int g = 0; g < 16; g += 2 * m) {
#pragma unroll
            for (int j = 0; j < m; j++) {
                float wr = W16R[j << mi];
                float wi = INV ? -W16I[j << mi] : W16I[j << mi];
                float2 a = v[g + j], b = v[g + j + m];
                float dx = a.x - b.x, dy = a.y - b.y;
                v[g + j] = make_float2(a.x + b.x, a.y + b.y);
                v[g + j + m] = make_float2(dx * wr - dy * wi, dx * wi + dy * wr);
            }
        }
    }
}

template <bool INV>
__device__ __forceinline__ void fft16_dit(float2 v[16]) {
#pragma unroll
    for (int mi = 3; mi >= 0; mi--) {
        const int m = 8 >> mi;
#pragma unroll
        for (int g = 0; g < 16; g += 2 * m) {
#pragma unroll
            for (int j = 0; j < m; j++) {
                float wr = W16R[j << mi];
                float wi = INV ? -W16I[j << mi] : W16I[j << mi];
                float2 a = v[g + j], b = v[g + j + m];
                float bx = b.x * wr - b.y * wi, by = b.x * wi + b.y * wr;
                v[g + j] = make_float2(a.x + bx, a.y + by);
                v[g + j + m] = make_float2(a.x - bx, a.y - by);
            }
        }
    }
}

template <bool INV>
__device__ __forceinline__ void fft8_dif(float2 v[8]) {
#pragma unroll
    for (int mi = 0; mi < 3; mi++) {
        const int m = 4 >> mi;
#pragma unroll
        for (int g = 0; g < 8; g += 2 * m) {
#pragma unroll
            for (int j = 0; j < m; j++) {
                float wr = W16R[j << (mi + 1)];
                float wi = INV ? -W16I[j << (mi + 1)] : W16I[j << (mi + 1)];
                float2 a = v[g + j], b = v[g + j + m];
                float dx = a.x - b.x, dy = a.y - b.y;
                v[g + j] = make_float2(a.x + b.x, a.y + b.y);
                v[g + j + m] = make_float2(dx * wr - dy * wi, dx * wi + dy * wr);
            }
        }
    }
}

// Pass A of the zero-padded (upper half) forward 4096 FFT, input in registers.
__device__ __forceinline__ void fft4096_passA_hz(float2* data, const float2* __restrict__ tw,
                                                 int t, const float2 vin[8]) {
    float2 v[16];
#pragma unroll
    for (int j = 0; j < 8; j++) v[j] = vin[j];
#pragma unroll
    for (int j = 0; j < 8; j++)
        v[j + 8] = cmulf(v[j], make_float2(W16R[j], W16I[j]));
#pragma unroll
    for (int mi = 1; mi < 4; mi++) {
        const int m = 8 >> mi;
#pragma unroll
        for (int g = 0; g < 16; g += 2 * m) {
#pragma unroll
            for (int j = 0; j < m; j++) {
                float wr = W16R[j << mi], wi = W16I[j << mi];
                float2 a = v[g + j], b = v[g + j + m];
                float dx = a.x - b.x, dy = a.y - b.y;
                v[g + j] = make_float2(a.x + b.x, a.y + b.y);
                v[g + j + m] = make_float2(dx * wr - dy * wi, dx * wi + dy * wr);
            }
        }
    }
#pragma unroll
    for (int i = 1; i < 16; i++) v[i] = cmulf(v[i], twget(tw, t * BR4[i]));
#pragma unroll
    for (int i = 0; i < 16; i++) data[sw(i * 256 + t)] = v[i];
}

// Passes B and C of the forward 4096 FFT (leading barrier included).
__device__ __forceinline__ void fft4096_fwd_BC(float2* data, const float2* __restrict__ tw, int t) {
    __syncthreads();
    {
        int j0 = t & 15;
        int base = (t >> 4) * 256 + j0;
        float2 v[16];
#pragma unroll
        for (int k = 0; k < 16; k++) v[k] = data[sw(base + 16 * k)];
        fft16_dif<false>(v);
#pragma unroll
        for (int i = 1; i < 16; i++) v[i] = cmulf(v[i], twget(tw, 16 * j0 * BR4[i]));
#pragma unroll
        for (int i = 0; i < 16; i++) data[sw(base + 16 * i)] = v[i];
    }
    __syncthreads();
    {
        float2 v[16];
#pragma unroll
        for (int k = 0; k < 16; k++) v[k] = data[sw(t * 16 + k)];
        fft16_dif<false>(v);
#pragma unroll
        for (int i = 0; i < 16; i++) data[sw(t * 16 + i)] = v[i];
    }
    __syncthreads();
}

// ---------------- kfft core: spectrum -> ifft2048 -> rfft4096 -> Kd (one (layer,h)) ----
// smem = 10240 floats (40KB). Overlay: pole tables (dead after Cauchy) and ktmp
// (born after fft8) BOTH live at [8192,10240) — lifetimes are barrier-separated;
// data float2[4096] = floats [0,8192) never touches that region.
__device__ __forceinline__ void kfft_core(int hh, int t, float* smem,
                                          float2* __restrict__ KdL,
                                          const float2* __restrict__ tw,
                                          const float* __restrict__ lam_re,
                                          const float* __restrict__ lam_im,
                                          const float* __restrict__ p_re,
                                          const float* __restrict__ p_im,
                                          const float* __restrict__ b_re,
                                          const float* __restrict__ b_im,
                                          const float* __restrict__ c_re,
                                          const float* __restrict__ c_im,
                                          const float* __restrict__ log_step) {
    float2* data = (float2*)smem;            // floats [0,8192)
    float4* polA = (float4*)(smem + 8192);   // floats [8192,8448)  (dead after Cauchy)
    float4* polB = (float4*)(smem + 8448);   // floats [8448,8704)
    float* n11S = smem + 8704;               // floats [8704,8768)
    float* ktmp = smem + 8192;               // floats [8192,10240) (born after fft8)
    int baseP = hh * Npol;
    if (t < Npol) {
        int n = t;
        float lr = lam_re[baseP + n], li = lam_im[baseP + n];
        float pr = p_re[baseP + n], pi = p_im[baseP + n];
        float br = b_re[baseP + n], bi = b_im[baseP + n];
        float cr = c_re[baseP + n], ci = c_im[baseP + n];
        polA[n] = make_float4(lr, li, cr * br + ci * bi, cr * bi - ci * br);
        polB[n] = make_float4(cr * pr + ci * pi, cr * pi - ci * pr,
                              pr * br + pi * bi, pr * bi - pi * br);
        n11S[n] = pr * pr + pi * pi;
    }
    __syncthreads();
    {   // ---- Cauchy spectrum: 8 l-positions per thread, into data[sw(l)] ----
        float step = expf(log_step[hh]);
        float gs = 2.0f / step;
        float wrv[8], wiv[8];
        float gr[8], gi[8];
#pragma unroll
        for (int j = 0; j < 8; j++) {
            int l = t + 256 * j;
            float ang = -6.283185307179586f * (float)l / (float)Lseq;
            float wr = cosf(ang), wi = sinf(ang);  // fp32 trig on purpose (see header)
            wrv[j] = wr; wiv[j] = wi;
            float dr = 1.0f + wr, di = wi;
            float invd2 = fast_rcp(dr * dr + di * di);
            float nr = 1.0f - wr, ni = -wi;
            gr[j] = gs * (nr * dr + ni * di) * invd2;
            gi[j] = gs * (ni * dr - nr * di) * invd2;
        }
        float k00x[8], k00y[8], k01x[8], k01y[8];
        float k10x[8], k10y[8], k11x[8], k11y[8];
#pragma unroll
        for (int j = 0; j < 8; j++) {
            k00x[j] = 0.f; k00y[j] = 0.f; k01x[j] = 0.f; k01y[j] = 0.f;
            k10x[j] = 0.f; k10y[j] = 0.f; k11x[j] = 0.f; k11y[j] = 0.f;
        }
        for (int n = 0; n < Npol; n++) {
            float4 A = polA[n];
            float4 B = polB[n];
            float n11 = n11S[n];
#pragma unroll
            for (int j = 0; j < 8; j++) {
                float er = gr[j] - A.x, ei = gi[j] - A.y;
                float inv2 = fast_rcp(fmaf(er, er, ei * ei));
                float ir = er * inv2;
                float mi = ei * inv2;
                k00x[j] = fmaf(A.z, ir, fmaf(A.w, mi, k00x[j]));
                k00y[j] = fmaf(A.w, ir, fmaf(-A.z, mi, k00y[j]));
                k01x[j] = fmaf(B.x, ir, fmaf(B.y, mi, k01x[j]));
                k01y[j] = fmaf(B.y, ir, fmaf(-B.x, mi, k01y[j]));
                k10x[j] = fmaf(B.z, ir, fmaf(B.w, mi, k10x[j]));
                k10y[j] = fmaf(B.w, ir, fmaf(-B.z, mi, k10y[j]));
                k11x[j] = fmaf(n11, ir, k11x[j]);
                k11y[j] = fmaf(-n11, mi, k11y[j]);
            }
        }
#pragma unroll
        for (int j = 0; j < 8; j++) {
            int l = t + 256 * j;
            float dr = 1.0f + wrv[j], di = wiv[j];
            float invd2 = fast_rcp(dr * dr + di * di);
            float cr2 = 2.0f * dr * invd2, ci2 = -2.0f * di * invd2;
            float wr2 = 1.0f + k11x[j], wi2 = k11y[j];
            float w2inv = fast_rcp(fmaf(wr2, wr2, wi2 * wi2));
            float vr = wr2 * w2inv, vi = -wi2 * w2inv;
            float t1x = k01x[j] * k10x[j] - k01y[j] * k10y[j];
            float t1y = k01x[j] * k10y[j] + k01y[j] * k10x[j];
            float t2x = t1x * vr - t1y * vi, t2y = t1x * vi + t1y * vr;
            float ex = k00x[j] - t2x, ey = k00y[j] - t2y;
            data[sw(l)] = make_float2(cr2 * ex - ci2 * ey, cr2 * ey + ci2 * ex);
        }
    }
    __syncthreads();
    if (t < 128) {
        float2 v[16];
#pragma unroll
        for (int k = 0; k < 16; k++) v[k] = data[sw(t + 128 * k)];
        fft16_dif<true>(v);
#pragma unroll
        for (int i = 1; i < 16; i++) v[i] = cmulc(v[i], twget(tw, 2 * t * BR4[i]));
#pragma unroll
        for (int i = 0; i < 16; i++) data[sw(i * 128 + t)] = v[i];
    }
    __syncthreads();
    if (t < 128) {
        int i2 = t >> 3, j0 = t & 7;
        int base2 = i2 * 128 + j0;
        float2 v[16];
#pragma unroll
        for (int k = 0; k < 16; k++) v[k] = data[sw(base2 + 8 * k)];
        fft16_dif<true>(v);
#pragma unroll
        for (int i = 1; i < 16; i++) v[i] = cmulc(v[i], twget(tw, 32 * j0 * BR4[i]));
#pragma unroll
        for (int i = 0; i < 16; i++) data[sw(base2 + 8 * i)] = v[i];
    }
    __syncthreads();
    {
        float2 v8[8];
#pragma unroll
        for (int k = 0; k < 8; k++) v8[k] = data[sw(t * 8 + k)];
        fft8_dif<true>(v8);
        int r = BR4[t >> 4], s = BR4[t & 15];
#pragma unroll
        for (int i = 0; i < 8; i++) {
            int l = r + 16 * s + 256 * BR3[i];
            ktmp[l] = v8[i].x * (1.0f / 2048.0f);
        }
    }
    __syncthreads();
    {
        float2 vin[8];
#pragma unroll
        for (int k = 0; k < 8; k++) vin[k] = make_float2(ktmp[t + 256 * k], 0.f);
        fft4096_passA_hz(data, tw, t, vin);
    }
    fft4096_fwd_BC(data, tw, t);
    float2* dst = KdL + (size_t)hh * 4096;
#pragma unroll
    for (int k = 0; k < 16; k++) {
        int p = t + 256 * k;
        dst[p] = data[sw(p)];
    }
}

// ---------------- prep: twiddle + bf16 weights (w1,w2,dec_w,enc_w) ----------------
__global__ __launch_bounds__(256, 4) void prep_kernel(const float* __restrict__ w1,
                                                      const float* __restrict__ w2,
                                                      const float* __restrict__ dec_w,
                                                      const float* __restrict__ enc_w,
                                                      float2* __restrict__ tw,
                                                      __bf16* __restrict__ wbf,
                                                      __bf16* __restrict__ decbf,
                                                      __bf16* __restrict__ encbf) {
    int bid = blockIdx.x, t = threadIdx.x;
    if (bid < 8) {
        int k = bid * 256 + t;
        if (k < 2048) {
            double a = -6.283185307179586476925286766559 * (double)k / 4096.0;
            tw[k] = make_float2((float)cos(a), (float)sin(a));
        }
        return;
    }
    if (bid < 264) {
        int i = (bid - 8) * 256 + t;
        int layer = i >> 14, rem = i & 16383;
        wbf[((size_t)layer * 2) * 16384 + rem] = (__bf16)w1[i];
        wbf[((size_t)layer * 2 + 1) * 16384 + rem] = (__bf16)w2[i];
        return;
    }
    if (bid < 296) {  // dec_w (64x128) -> bf16
        int i = (bid - 264) * 256 + t;
        decbf[i] = (__bf16)dec_w[i];
        return;
    }
    // enc_w (128x64) -> bf16
    int i = (bid - 296) * 256 + t;
    encbf[i] = (__bf16)enc_w[i];
}

// ---------------- kfft (all layers) + MFMA encoder merged ----------------
// kfft blocks [0,512): Kd[layer= bid>>7][h= bid&127].
// encoder blocks [512,1024): bf16 MFMA encoder + fused LN, 32 rows/block.
// 1024 blocks x 40KB LDS = exactly 4 blocks/CU -> whole grid co-resident.
__global__ __launch_bounds__(256) void kfft_enc_kernel(float2* __restrict__ Kd1,
                                                       const float2* __restrict__ tw,
                                                       const float* __restrict__ x,
                                                       const __bf16* __restrict__ encbf,
                                                       const float* __restrict__ enc_b,
                                                       const float* __restrict__ nw,
                                                       const float* __restrict__ nb,
                                                       float* __restrict__ h,
                                                       float* __restrict__ hnT,
                                                       const float* __restrict__ lam_re,
                                                       const float* __restrict__ lam_im,
                                                       const float* __restrict__ p_re,
                                                       const float* __restrict__ p_im,
                                                       const float* __restrict__ b_re,
                                                       const float* __restrict__ b_im,
                                                       const float* __restrict__ c_re,
                                                       const float* __restrict__ c_im,
                                                       const float* __restrict__ log_step) {
    __shared__ __align__(16) float smem[10240];
    int bid = blockIdx.x, t = threadIdx.x;
    if (bid < 512) {
        int hh = bid & 127, layer = bid >> 7;
        int PN = Hdim * Npol;
        kfft_core(hh, t, smem, Kd1 + (size_t)layer * Hdim * 4096, tw,
                  lam_re + layer * PN, lam_im + layer * PN,
                  p_re + layer * PN, p_im + layer * PN,
                  b_re + layer * PN, b_im + layer * PN,
                  c_re + layer * PN, c_im + layer * PN,
                  log_step + layer * Hdim);
    } else {
        // ---- encoder via bf16 MFMA + fused LN: 32 rows/block ----
        int r0 = (bid - 512) * 32;
        __bf16* ybf = (__bf16*)smem;              // 32*72 bf16
        float* dots = smem + 1152;                // 32*132 floats
        float2* mv = (float2*)(smem + 5376);      // 32 float2
        int bb = r0 >> 11, l0 = r0 & 2047;
        for (int i = t; i < 32 * 64; i += 256) {
            int r = i >> 6, k = i & 63;
            ybf[r * 72 + k] = (__bf16)x[(size_t)(r0 + r) * 64 + k];
        }
        __syncthreads();
        int wave = t >> 6, lane = t & 63;
        int m = lane & 31, half = lane >> 5;
        bf16x8 a[4];
#pragma unroll
        for (int kk = 0; kk < 4; kk++)
            a[kk] = *(const bf16x8*)&ybf[m * 72 + kk * 16 + half * 8];
        int o = 32 * wave + m;
        const __bf16* wr = encbf + (size_t)o * 64 + half * 8;
        f32x16 acc;
#pragma unroll
        for (int i = 0; i < 16; i++) acc[i] = 0.f;
#pragma unroll
        for (int kk = 0; kk < 4; kk++) {
            bf16x8 bw = *(const bf16x8*)(wr + kk * 16);
            acc = __builtin_amdgcn_mfma_f32_32x32x16_bf16(a[kk], bw, acc, 0, 0, 0);
        }
        float bo = enc_b[o];
#pragma unroll
        for (int reg = 0; reg < 16; reg++) {
            int row = (reg & 3) + 8 * (reg >> 2) + 4 * half;
            dots[row * 132 + o] = acc[reg] + bo;
        }
        __syncthreads();
        {
            int row = t >> 3, lane8 = t & 7;
            float s1 = 0.f, s2 = 0.f;
            int base = row * 132 + lane8 * 16;
#pragma unroll
            for (int q = 0; q < 4; q++) {
                float4 v4 = *(const float4*)&dots[base + 4 * q];
                s1 += v4.x + v4.y + v4.z + v4.w;
                s2 += v4.x * v4.x + v4.y * v4.y + v4.z * v4.z + v4.w * v4.w;
            }
#pragma unroll
            for (int mm = 1; mm < 8; mm <<= 1) { s1 += __shfl_xor(s1, mm); s2 += __shfl_xor(s2, mm); }
            if (lane8 == 0) {
                float mu = s1 * (1.0f / 128.0f);
                float var = s2 * (1.0f / 128.0f) - mu * mu;
                mv[row] = make_float2(mu, fast_rsq(var + 1e-5f));
            }
        }
        __syncthreads();
        {
            int o2 = t & 127, rh = t >> 7;
            float nwc = nw[o2], nbc = nb[o2];
            float hnv[16];
#pragma unroll
            for (int j = 0; j < 16; j++) {
                int r = rh * 16 + j;
                float hvv = dots[r * 132 + o2];
                h[(size_t)(r0 + r) * Hdim + o2] = hvv;
                float2 mvv = mv[r];
                hnv[j] = (hvv - mvv.x) * mvv.y * nwc + nbc;
            }
            float* dst = hnT + ((size_t)bb * Hdim + o2) * Lseq + l0 + rh * 16;
            *(float4*)(dst)      = make_float4(hnv[0],  hnv[1],  hnv[2],  hnv[3]);
            *(float4*)(dst + 4)  = make_float4(hnv[4],  hnv[5],  hnv[6],  hnv[7]);
            *(float4*)(dst + 8)  = make_float4(hnv[8],  hnv[9],  hnv[10], hnv[11]);
            *(float4*)(dst + 12) = make_float4(hnv[12], hnv[13], hnv[14], hnv[15]);
        }
    }
}

// ---------------- FFT convolution: batch-pair packing, radix-16^3 ----------------
// 1D grid, XCD-aware decode: bid = (h&7) + 8*((h>>3)*4 + bp) -> same-h blocks
// share bid%8 (= XCD under round-robin), so the 32KB Kd slice is read once from
// HBM and 3x from that XCD's L2.
__global__ __launch_bounds__(256) void conv_kernel(float* __restrict__ hnT,
                                                   const float2* __restrict__ Kd1,
                                                   const float* __restrict__ dvec,
                                                   const float2* __restrict__ tw) {
    int bid = blockIdx.x, t = threadIdx.x;
    int xcd = bid & 7, rest = bid >> 3;
    int h = xcd + 8 * (rest >> 2);
    int bp = rest & 3;
    __shared__ float2 data[4096];
    float* u0 = hnT + ((size_t)(2 * bp) * Hdim + h) * Lseq;
    float* u1 = hnT + ((size_t)(2 * bp + 1) * Hdim + h) * Lseq;
    float2 ureg[8];
    float2 Kreg[16];
    float2 twB[15];
    const int j0 = t & 15;
    const float4* Kp4 = (const float4*)(Kd1 + (size_t)h * 4096 + t * 16);
    {   // pruned pass A: input upper half zero, from registers. Kd + B-twiddle
        // prefetch issued alongside the u loads so latency hides under the fwd FFT.
        float2 vin[8];
#pragma unroll
        for (int k = 0; k < 8; k++) {
            int l = t + 256 * k;
            float2 u2 = make_float2(u0[l], u1[l]);
            ureg[k] = u2;
            vin[k] = u2;
        }
#pragma unroll
        for (int k = 0; k < 8; k++) {
            float4 q = Kp4[k];
            Kreg[2 * k]     = make_float2(q.x, q.y);
            Kreg[2 * k + 1] = make_float2(q.z, q.w);
        }
#pragma unroll
        for (int i = 1; i < 16; i++) twB[i - 1] = twget(tw, 16 * j0 * BR4[i]);
        fft4096_passA_hz(data, tw, t, vin);
    }
    __syncthreads();
    {   // forward pass B (register twiddles)
        int base = (t >> 4) * 256 + j0;
        float2 v[16];
#pragma unroll
        for (int k = 0; k < 16; k++) v[k] = data[sw(base + 16 * k)];
        fft16_dif<false>(v);
#pragma unroll
        for (int i = 1; i < 16; i++) v[i] = cmulf(v[i], twB[i - 1]);
#pragma unroll
        for (int i = 0; i < 16; i++) data[sw(base + 16 * i)] = v[i];
    }
    __syncthreads();
    {   // fused: forward pass C -> pointwise *Kd*scale -> inverse pass C'
        const float scale = 1.0f / 4096.0f;
        float2 v[16];
#pragma unroll
        for (int k = 0; k < 16; k++) v[k] = data[sw(t * 16 + k)];
        fft16_dif<false>(v);
#pragma unroll
        for (int i = 0; i < 16; i++) {
            float2 W = cmulf(v[i], Kreg[i]);
            v[i] = make_float2(W.x * scale, W.y * scale);
        }
        fft16_dit<true>(v);
#pragma unroll
        for (int i = 0; i < 16; i++) data[sw(t * 16 + i)] = v[i];
    }
    __syncthreads();
    {   // inverse pass B' (register twiddles, conjugated)
        int base2 = (t >> 4) * 256 + j0;
        float2 v[16];
        v[0] = data[sw(base2)];
#pragma unroll
        for (int i = 1; i < 16; i++)
            v[i] = cmulc(data[sw(base2 + 16 * i)], twB[i - 1]);
        fft16_dit<true>(v);
#pragma unroll
        for (int i = 0; i < 16; i++) data[sw(base2 + 16 * i)] = v[i];
    }
    __syncthreads();
    {   // inverse pass A': final stage pruned to the needed output half (l < 2048)
        float2 v[16];
        v[0] = data[sw(t)];
#pragma unroll
        for (int i = 1; i < 16; i++)
            v[i] = cmulc(data[sw(i * 256 + t)], twget(tw, t * BR4[i]));
#pragma unroll
        for (int mi = 3; mi >= 1; mi--) {
            const int m = 8 >> mi;
#pragma unroll
            for (int g = 0; g < 16; g += 2 * m) {
#pragma unroll
                for (int j = 0; j < m; j++) {
                    float wr = W16R[j << mi], wi = -W16I[j << mi];
                    float2 a = v[g + j], bb2 = v[g + j + m];
                    float bx = bb2.x * wr - bb2.y * wi, by = bb2.x * wi + bb2.y * wr;
                    v[g + j] = make_float2(a.x + bx, a.y + by);
                    v[g + j + m] = make_float2(a.x - bx, a.y - by);
                }
            }
        }
#pragma unroll
        for (int j = 0; j < 8; j++) {
            float wr = W16R[j], wi = -W16I[j];
            float2 bb2 = v[j + 8];
            float bx = bb2.x * wr - bb2.y * wi, by = bb2.x * wi + bb2.y * wr;
            v[j] = make_float2(v[j].x + bx, v[j].y + by);
        }
        float dcoef = dvec[h];
#pragma unroll
        for (int k = 0; k < 8; k++) {
            int l = t + 256 * k;
            u0[l] = gelu_f(v[k].x + ureg[k].x * dcoef);
            u1[l] = gelu_f(v[k].y + ureg[k].y * dcoef);
        }
    }
}

// ---------------- gated MLP via bf16 MFMA + residual + fused LN: 32 rows/block ----------------
__global__ __launch_bounds__(256) void mlp_kernel(const float* __restrict__ yT,
                                                  float* __restrict__ h,
                                                  float* __restrict__ hnT,
                                                  const __bf16* __restrict__ w1b,
                                                  const __bf16* __restrict__ w2b,
                                                  const float* __restrict__ b1,
                                                  const float* __restrict__ b2,
                                                  const float* __restrict__ nw,
                                                  const float* __restrict__ nb) {
    int r0 = blockIdx.x * 32;
    int t = threadIdx.x;
    int wave = t >> 6, lane = t & 63;
    __shared__ __align__(16) __bf16 ybf[32 * 136];
    __shared__ float dots[32 * 132];
    __shared__ float2 mv[32];
    int bb = r0 >> 11, l0 = r0 & 2047;
    for (int i = t; i < 32 * 128; i += 256) {
        int r = i & 31, k = i >> 5;
        ybf[r * 136 + k] = (__bf16)yT[((size_t)bb * Hdim + k) * Lseq + l0 + r];
    }
    __syncthreads();
    int m = lane & 31, half = lane >> 5;
    bf16x8 a[8];
#pragma unroll
    for (int kk = 0; kk < 8; kk++)
        a[kk] = *(const bf16x8*)&ybf[m * 136 + kk * 16 + half * 8];
    int out = 32 * wave + m;
    const __bf16* w1r = w1b + (size_t)out * 128 + half * 8;
    const __bf16* w2r = w2b + (size_t)out * 128 + half * 8;
    f32x16 acc1, acc2;
#pragma unroll
    for (int i = 0; i < 16; i++) { acc1[i] = 0.f; acc2[i] = 0.f; }
#pragma unroll
    for (int kk = 0; kk < 8; kk++) {
        bf16x8 bw1 = *(const bf16x8*)(w1r + kk * 16);
        bf16x8 bw2 = *(const bf16x8*)(w2r + kk * 16);
        acc1 = __builtin_amdgcn_mfma_f32_32x32x16_bf16(a[kk], bw1, acc1, 0, 0, 0);
        acc2 = __builtin_amdgcn_mfma_f32_32x32x16_bf16(a[kk], bw2, acc2, 0, 0, 0);
    }
    float bias1 = b1[out], bias2 = b2[out];
#pragma unroll
    for (int reg = 0; reg < 16; reg++) {
        int row = (reg & 3) + 8 * (reg >> 2) + 4 * half;
        float v1 = acc1[reg] + bias1;
        float v2 = acc2[reg] + bias2;
        float g = fast_rcp(1.0f + __expf(-v2));
        float hv = h[(size_t)(r0 + row) * Hdim + out] + v1 * g;
        dots[row * 132 + out] = hv;
    }
    __syncthreads();
    {
        int row = t >> 3, lane8 = t & 7;
        float s1 = 0.f, s2 = 0.f;
        int base = row * 132 + lane8 * 16;
#pragma unroll
        for (int q = 0; q < 4; q++) {
            float4 v4 = *(const float4*)&dots[base + 4 * q];
            s1 += v4.x + v4.y + v4.z + v4.w;
            s2 += v4.x * v4.x + v4.y * v4.y + v4.z * v4.z + v4.w * v4.w;
        }
#pragma unroll
        for (int mm = 1; mm < 8; mm <<= 1) { s1 += __shfl_xor(s1, mm); s2 += __shfl_xor(s2, mm); }
        if (lane8 == 0) {
            float mu = s1 * (1.0f / 128.0f);
            float var = s2 * (1.0f / 128.0f) - mu * mu;
            mv[row] = make_float2(mu, fast_rsq(var + 1e-5f));
        }
    }
    __syncthreads();
    {
        int o = t & 127, rh = t >> 7;
        float nwc = nw[o], nbc = nb[o];
        float hnv[16];
#pragma unroll
        for (int j = 0; j < 16; j++) {
            int r = rh * 16 + j;
            float hvv = dots[r * 132 + o];
            h[(size_t)(r0 + r) * Hdim + o] = hvv;
            float2 mvv = mv[r];
            hnv[j] = (hvv - mvv.x) * mvv.y * nwc + nbc;
        }
        float* dst = hnT + ((size_t)bb * Hdim + o) * Lseq + l0 + rh * 16;
        *(float4*)(dst)      = make_float4(hnv[0],  hnv[1],  hnv[2],  hnv[3]);
        *(float4*)(dst + 4)  = make_float4(hnv[4],  hnv[5],  hnv[6],  hnv[7]);
        *(float4*)(dst + 8)  = make_float4(hnv[8],  hnv[9],  hnv[10], hnv[11]);
        *(float4*)(dst + 12) = make_float4(hnv[12], hnv[13], hnv[14], hnv[15]);
    }
}

// ---------------- last layer: gated MLP + residual + fused DECODER (bf16 MFMA) ----------
__global__ __launch_bounds__(256) void mlpdec_kernel(const float* __restrict__ yT,
                                                     const float* __restrict__ h,
                                                     const __bf16* __restrict__ w1b,
                                                     const __bf16* __restrict__ w2b,
                                                     const float* __restrict__ b1,
                                                     const float* __restrict__ b2,
                                                     const __bf16* __restrict__ decb,
                                                     const float* __restrict__ dec_bias,
                                                     float* __restrict__ out) {
    int r0 = blockIdx.x * 32;
    int t = threadIdx.x;
    int wave = t >> 6, lane = t & 63;
    __shared__ __align__(16) __bf16 ybf[32 * 136];
    __shared__ float dots[32 * 132];
    int bb = r0 >> 11, l0 = r0 & 2047;
    for (int i = t; i < 32 * 128; i += 256) {
        int r = i & 31, k = i >> 5;
        ybf[r * 136 + k] = (__bf16)yT[((size_t)bb * Hdim + k) * Lseq + l0 + r];
    }
    __syncthreads();
    int m = lane & 31, half = lane >> 5;
    bf16x8 a[8];
#pragma unroll
    for (int kk = 0; kk < 8; kk++)
        a[kk] = *(const bf16x8*)&ybf[m * 136 + kk * 16 + half * 8];
    int outc = 32 * wave + m;
    const __bf16* w1r = w1b + (size_t)outc * 128 + half * 8;
    const __bf16* w2r = w2b + (size_t)outc * 128 + half * 8;
    f32x16 acc1, acc2;
#pragma unroll
    for (int i = 0; i < 16; i++) { acc1[i] = 0.f; acc2[i] = 0.f; }
#pragma unroll
    for (int kk = 0; kk < 8; kk++) {
        bf16x8 bw1 = *(const bf16x8*)(w1r + kk * 16);
        bf16x8 bw2 = *(const bf16x8*)(w2r + kk * 16);
        acc1 = __builtin_amdgcn_mfma_f32_32x32x16_bf16(a[kk], bw1, acc1, 0, 0, 0);
        acc2 = __builtin_amdgcn_mfma_f32_32x32x16_bf16(a[kk], bw2, acc2, 0, 0, 0);
    }
    float bias1 = b1[outc], bias2 = b2[outc];
#pragma unroll
    for (int reg = 0; reg < 16; reg++) {
        int row = (reg & 3) + 8 * (reg >> 2) + 4 * half;
        float v1 = acc1[reg] + bias1;
        float v2 = acc2[reg] + bias2;
        float g = fast_rcp(1.0f + __expf(-v2));
        float hv = h[(size_t)(r0 + row) * Hdim + outc] + v1 * g;
        dots[row * 132 + outc] = hv;
    }
    __syncthreads();
    // restage h tile as bf16 A-operands
    for (int i = t; i < 32 * 128; i += 256) {
        int r = i >> 7, k = i & 127;
        ybf[r * 136 + k] = (__bf16)dots[r * 132 + k];
    }
    __syncthreads();
    if (wave < 2) {  // decoder GEMM: 32 rows x 64 outs, K=128
        bf16x8 a2[8];
#pragma unroll
        for (int kk = 0; kk < 8; kk++)
            a2[kk] = *(const bf16x8*)&ybf[m * 136 + kk * 16 + half * 8];
        int oc = 32 * wave + m;  // 0..63
        const __bf16* wr = decb + (size_t)oc * 128 + half * 8;
        f32x16 acc;
#pragma unroll
        for (int i = 0; i < 16; i++) acc[i] = 0.f;
#pragma unroll
        for (int kk = 0; kk < 8; kk++) {
            bf16x8 bw = *(const bf16x8*)(wr + kk * 16);
            acc = __builtin_amdgcn_mfma_f32_32x32x16_bf16(a2[kk], bw, acc, 0, 0, 0);
        }
        float bo = dec_bias[oc];
#pragma unroll
        for (int reg = 0; reg < 16; reg++) {
            int row = (reg & 3) + 8 * (reg >> 2) + 4 * half;
            out[(size_t)(r0 + row) * 64 + oc] = acc[reg] + bo;
        }
    }
}

extern "C" void kernel_launch(void* const* d_in, const int* in_sizes, int n_in,
                              void* d_out, int out_size, void* d_ws, size_t ws_size,
                              hipStream_t stream) {
    const float* x      = (const float*)d_in[0];
    const float* enc_w  = (const float*)d_in[2];
    const float* enc_b  = (const float*)d_in[3];
    const float* dec_w  = (const float*)d_in[4];
    const float* dec_b  = (const float*)d_in[5];
    const float* lam_re = (const float*)d_in[6];
    const float* lam_im = (const float*)d_in[7];
    const float* p_re   = (const float*)d_in[8];
    const float* p_im   = (const float*)d_in[9];
    const float* b_re   = (const float*)d_in[10];
    const float* b_im   = (const float*)d_in[11];
    const float* c_re   = (const float*)d_in[12];
    const float* c_im   = (const float*)d_in[13];
    const float* dvec   = (const float*)d_in[14];
    const float* lstep  = (const float*)d_in[15];
    const float* norm_w = (const float*)d_in[16];
    const float* norm_b = (const float*)d_in[17];
    const float* w1     = (const float*)d_in[18];
    const float* b1     = (const float*)d_in[19];
    const float* w2     = (const float*)d_in[20];
    const float* b2     = (const float*)d_in[21];
    float* out = (float*)d_out;

    char* ws = (char*)d_ws;
    float2* tw  = (float2*)ws;  ws += 2048 * sizeof(float2);
    float*  h   = (float*)ws;   ws += (size_t)Bsz * Lseq * Hdim * sizeof(float);
    float*  hnT = (float*)ws;   ws += (size_t)Bsz * Lseq * Hdim * sizeof(float);
    float2* Kd1 = (float2*)ws;  ws += (size_t)NLAYERS * Hdim * 4096 * sizeof(float2);
    __bf16* wbf = (__bf16*)ws;  ws += (size_t)NLAYERS * 2 * Hdim * Hdim * sizeof(__bf16);
    __bf16* dbf = (__bf16*)ws;  ws += (size_t)64 * Hdim * sizeof(__bf16);
    __bf16* ebf = (__bf16*)ws;  ws += (size_t)Hdim * 64 * sizeof(__bf16);

    const int nrows = Bsz * Lseq;  // 16384

    prep_kernel<<<328, 256, 0, stream>>>(w1, w2, dec_w, enc_w, tw, wbf, dbf, ebf);
    kfft_enc_kernel<<<512 + nrows / 32, 256, 0, stream>>>(
        Kd1, tw, x, ebf, enc_b, norm_w, norm_b, h, hnT,
        lam_re, lam_im, p_re, p_im, b_re, b_im, c_re, c_im, lstep);
    for (int L = 0; L < NLAYERS; L++) {
        conv_kernel<<<512, 256, 0, stream>>>(
            hnT, Kd1 + (size_t)L * Hdim * 4096, dvec + L * Hdim, tw);
        const __bf16* w1bL = wbf + (size_t)L * 2 * Hdim * Hdim;
        const __bf16* w2bL = w1bL + Hdim * Hdim;
        if (L < NLAYERS - 1) {
            const float* nwn = norm_w + (L + 1) * Hdim;
            const float* nbn = norm_b + (L + 1) * Hdim;
            mlp_kernel<<<nrows / 32, 256, 0, stream>>>(hnT, h, hnT, w1bL, w2bL,
                                                       b1 + L * Hdim, b2 + L * Hdim,
                                                       nwn, nbn);
        } else {
            mlpdec_kernel<<<nrows / 32, 256, 0, stream>>>(hnT, h, w1bL, w2bL,
                                                          b1 + L * Hdim, b2 + L * Hdim,
                                                          dbf, dec_b, out);
        }
    }
}

// Round 13
// 265.437 us; speedup vs baseline: 1.1824x; 1.0524x over previous
//
#include <hip/hip_runtime.h>
#include <hip/hip_bf16.h>

// S4 (DPLR) forward, B=8 L=2048 IN=OUT=64 H=128 N=64, 4 layers.
// R29 = R28 resubmitted (previous round failed on container acquisition, not on
// the kernel). Changes vs R25: (1) kfft_enc rebuilt on 512-thread blocks:
// Cauchy runs 4 freqs/thread across 8 waves (halved serial chain, 2x wave
// parallelism during the straggler tail); FFT phases keep their 128/256-thread
// shapes behind t<256 guards with barriers hoisted outside. Encoder rides along
// guarded to t<256. (2) conv writes y directly as bf16 (its only consumer is
// mlp's bf16 A-operand conversion -> identical rounding point, absmax
// unchanged; write+read traffic halves). omega via cosf/sinf on purpose
// (l=1024 bilinear singularity regularized by fp32 trig rounding).

#define Bsz 8
#define Lseq 2048
#define Hdim 128
#define Npol 64
#define NLAYERS 4

typedef __bf16 bf16x8 __attribute__((ext_vector_type(8)));
typedef float f32x16 __attribute__((ext_vector_type(16)));

__device__ __forceinline__ float fast_rcp(float x) { return __builtin_amdgcn_rcpf(x); }
__device__ __forceinline__ float fast_rsq(float x) { return __builtin_amdgcn_rsqf(x); }

__device__ __forceinline__ float2 cmulf(float2 a, float2 b) {
    return make_float2(a.x * b.x - a.y * b.y, a.x * b.y + a.y * b.x);
}
__device__ __forceinline__ float2 cmulc(float2 a, float2 b) {  // a * conj(b)
    return make_float2(a.x * b.x + a.y * b.y, a.y * b.x - a.x * b.y);
}

__device__ __forceinline__ float gelu_f(float v) {
    float z = 0.7978845608028654f * (v + 0.044715f * v * v * v);
    float e = __expf(2.0f * z);
    return v - v * fast_rcp(e + 1.0f);
}

// XOR swizzle: strides 1/16/256 all conflict-uniform for the 4096 arrays.
__device__ __forceinline__ int sw(int i) { return (i & ~15) | ((i ^ (i >> 4)) & 15); }

static __device__ const float W16R[8] = {1.f, 0.9238795325f, 0.7071067812f, 0.3826834324f,
                                         0.f, -0.3826834324f, -0.7071067812f, -0.9238795325f};
static __device__ const float W16I[8] = {0.f, -0.3826834324f, -0.7071067812f, -0.9238795325f,
                                         -1.f, -0.9238795325f, -0.7071067812f, -0.3826834324f};
static __device__ const int BR4[16] = {0, 8, 4, 12, 2, 10, 6, 14, 1, 9, 5, 13, 3, 11, 7, 15};
static __device__ const int BR3[8] = {0, 4, 2, 6, 1, 5, 3, 7};

__device__ __forceinline__ float2 twget(const float2* __restrict__ tw, int e) {
    float2 w = tw[e & 2047];
    if (e & 2048) { w.x = -w.x; w.y = -w.y; }
    return w;
}

template <bool INV>
__device__ __forceinline__ void fft16_dif(float2 v[16]) {
#pragma unroll
    for (int mi = 0; mi < 4; mi++) {
        const int m = 8 >> mi;
#pragma unroll
        for (int g = 0; g < 16; g += 2 * m) {
#pragma unroll
            for (int j = 0; j < m; j++) {
                float wr = W16R[j << mi];
                float wi = INV ? -W16I[j << mi] : W16I[j << mi];
                float2 a = v[g + j], b = v[g + j + m];
                float dx = a.x - b.x, dy = a.y - b.y;
                v[g + j] = make_float2(a.x + b.x, a.y + b.y);
                v[g + j + m] = make_float2(dx * wr - dy * wi, dx * wi + dy * wr);
            }
        }
    }
}

template <bool INV>
__device__ __forceinline__ void fft16_dit(float2 v[16]) {
#pragma unroll
    for (int mi = 3; mi >= 0; mi--) {
        const int m = 8 >> mi;
#pragma unroll
        for (int g = 0; g < 16; g += 2 * m) {
#pragma unroll
            for (int j = 0; j < m; j++) {
                float wr = W16R[j << mi];
                float wi = INV ? -W16I[j << mi] : W16I[j << mi];
                float2 a = v[g + j], b = v[g + j + m];
                float bx = b.x * wr - b.y * wi, by = b.x * wi + b.y * wr;
                v[g + j] = make_float2(a.x + bx, a.y + by);
                v[g + j + m] = make_float2(a.x - bx, a.y - by);
            }
        }
    }
}

template <bool INV>
__device__ __forceinline__ void fft8_dif(float2 v[8]) {
#pragma unroll
    for (int mi = 0; mi < 3; mi++) {
        const int m = 4 >> mi;
#pragma unroll
        for (int g = 0; g < 8; g += 2 * m) {
#pragma unroll
            for (int j = 0; j < m; j++) {
                float wr = W16R[j << (mi + 1)];
                float wi = INV ? -W16I[j << (mi + 1)] : W16I[j << (mi + 1)];
                float2 a = v[g + j], b = v[g + j + m];
                float dx = a.x - b.x, dy = a.y - b.y;
                v[g + j] = make_float2(a.x + b.x, a.y + b.y);
                v[g + j + m] = make_float2(dx * wr - dy * wi, dx * wi + dy * wr);
            }
        }
    }
}

// Pass A of the zero-padded (upper half) forward 4096 FFT, input in registers.
__device__ __forceinline__ void fft4096_passA_hz(float2* data, const float2* __restrict__ tw,
                                                 int t, const float2 vin[8]) {
    float2 v[16];
#pragma unroll
    for (int j = 0; j < 8; j++) v[j] = vin[j];
#pragma unroll
    for (int j = 0; j < 8; j++)
        v[j + 8] = cmulf(v[j], make_float2(W16R[j], W16I[j]));
#pragma unroll
    for (int mi = 1; mi < 4; mi++) {
        const int m = 8 >> mi;
#pragma unroll
        for (int g = 0; g < 16; g += 2 * m) {
#pragma unroll
            for (int j = 0; j < m; j++) {
                float wr = W16R[j << mi], wi = W16I[j << mi];
                float2 a = v[g + j], b = v[g + j + m];
                float dx = a.x - b.x, dy = a.y - b.y;
                v[g + j] = make_float2(a.x + b.x, a.y + b.y);
                v[g + j + m] = make_float2(dx * wr - dy * wi, dx * wi + dy * wr);
            }
        }
    }
#pragma unroll
    for (int i = 1; i < 16; i++) v[i] = cmulf(v[i], twget(tw, t * BR4[i]));
#pragma unroll
    for (int i = 0; i < 16; i++) data[sw(i * 256 + t)] = v[i];
}

// Passes B and C of the forward 4096 FFT (256-thread t).
__device__ __forceinline__ void fft4096_fwd_B(float2* data, const float2* __restrict__ tw, int t) {
    int j0 = t & 15;
    int base = (t >> 4) * 256 + j0;
    float2 v[16];
#pragma unroll
    for (int k = 0; k < 16; k++) v[k] = data[sw(base + 16 * k)];
    fft16_dif<false>(v);
#pragma unroll
    for (int i = 1; i < 16; i++) v[i] = cmulf(v[i], twget(tw, 16 * j0 * BR4[i]));
#pragma unroll
    for (int i = 0; i < 16; i++) data[sw(base + 16 * i)] = v[i];
}
__device__ __forceinline__ void fft4096_fwd_C(float2* data, int t) {
    float2 v[16];
#pragma unroll
    for (int k = 0; k < 16; k++) v[k] = data[sw(t * 16 + k)];
    fft16_dif<false>(v);
#pragma unroll
    for (int i = 0; i < 16; i++) data[sw(t * 16 + i)] = v[i];
}

// ---------------- prep: twiddle + bf16 weights (w1,w2,dec_w,enc_w) ----------------
__global__ __launch_bounds__(256, 4) void prep_kernel(const float* __restrict__ w1,
                                                      const float* __restrict__ w2,
                                                      const float* __restrict__ dec_w,
                                                      const float* __restrict__ enc_w,
                                                      float2* __restrict__ tw,
                                                      __bf16* __restrict__ wbf,
                                                      __bf16* __restrict__ decbf,
                                                      __bf16* __restrict__ encbf) {
    int bid = blockIdx.x, t = threadIdx.x;
    if (bid < 8) {
        int k = bid * 256 + t;
        if (k < 2048) {
            double a = -6.283185307179586476925286766559 * (double)k / 4096.0;
            tw[k] = make_float2((float)cos(a), (float)sin(a));
        }
        return;
    }
    if (bid < 264) {
        int i = (bid - 8) * 256 + t;
        int layer = i >> 14, rem = i & 16383;
        wbf[((size_t)layer * 2) * 16384 + rem] = (__bf16)w1[i];
        wbf[((size_t)layer * 2 + 1) * 16384 + rem] = (__bf16)w2[i];
        return;
    }
    if (bid < 296) {  // dec_w (64x128) -> bf16
        int i = (bid - 264) * 256 + t;
        decbf[i] = (__bf16)dec_w[i];
        return;
    }
    // enc_w (128x64) -> bf16
    int i = (bid - 296) * 256 + t;
    encbf[i] = (__bf16)enc_w[i];
}

// ---------------- kfft (all layers, 512-thread blocks) + encoder merged ----------------
// kfft blocks [0,512): Kd[layer][h]; Cauchy on all 8 waves (4 freqs/thread),
// FFT phases guarded to their natural 128/256-thread widths (barriers outside
// guards). encoder blocks [512,1024): original 256-thread code under t<256.
// 1024 blocks x 40KB LDS.
__global__ __launch_bounds__(512) void kfft_enc_kernel(float2* __restrict__ Kd1,
                                                       const float2* __restrict__ tw,
                                                       const float* __restrict__ x,
                                                       const __bf16* __restrict__ encbf,
                                                       const float* __restrict__ enc_b,
                                                       const float* __restrict__ nw,
                                                       const float* __restrict__ nb,
                                                       float* __restrict__ h,
                                                       float* __restrict__ hnT,
                                                       const float* __restrict__ lam_re,
                                                       const float* __restrict__ lam_im,
                                                       const float* __restrict__ p_re,
                                                       const float* __restrict__ p_im,
                                                       const float* __restrict__ b_re,
                                                       const float* __restrict__ b_im,
                                                       const float* __restrict__ c_re,
                                                       const float* __restrict__ c_im,
                                                       const float* __restrict__ log_step) {
    __shared__ __align__(16) float smem[10240];
    int bid = blockIdx.x, t = threadIdx.x;
    if (bid < 512) {
        int hh = bid & 127, layer = bid >> 7;
        int PN = Hdim * Npol;
        const float* lre = lam_re + layer * PN;
        const float* lim = lam_im + layer * PN;
        const float* pre = p_re + layer * PN;
        const float* pim = p_im + layer * PN;
        const float* bre = b_re + layer * PN;
        const float* bim = b_im + layer * PN;
        const float* cre = c_re + layer * PN;
        const float* cim = c_im + layer * PN;
        const float* lst = log_step + layer * Hdim;
        float2* data = (float2*)smem;            // floats [0,8192)
        float4* polA = (float4*)(smem + 8192);   // dead after Cauchy
        float4* polB = (float4*)(smem + 8448);
        float* n11S = smem + 8704;
        float* ktmp = smem + 8192;               // born after fft8
        int baseP = hh * Npol;
        if (t < Npol) {
            int n = t;
            float lr = lre[baseP + n], li = lim[baseP + n];
            float pr = pre[baseP + n], pi = pim[baseP + n];
            float br = bre[baseP + n], bi = bim[baseP + n];
            float cr = cre[baseP + n], ci = cim[baseP + n];
            polA[n] = make_float4(lr, li, cr * br + ci * bi, cr * bi - ci * br);
            polB[n] = make_float4(cr * pr + ci * pi, cr * pi - ci * pr,
                                  pr * br + pi * bi, pr * bi - pi * br);
            n11S[n] = pr * pr + pi * pi;
        }
        __syncthreads();
        {   // ---- Cauchy spectrum: 4 l-positions per thread (512 threads) ----
            float step = expf(lst[hh]);
            float gs = 2.0f / step;
            float wrv[4], wiv[4], gr[4], gi[4];
#pragma unroll
            for (int j = 0; j < 4; j++) {
                int l = t + 512 * j;
                float ang = -6.283185307179586f * (float)l / (float)Lseq;
                float wr = cosf(ang), wi = sinf(ang);  // fp32 trig on purpose
                wrv[j] = wr; wiv[j] = wi;
                float dr = 1.0f + wr, di = wi;
                float invd2 = fast_rcp(dr * dr + di * di);
                float nr = 1.0f - wr, ni = -wi;
                gr[j] = gs * (nr * dr + ni * di) * invd2;
                gi[j] = gs * (ni * dr - nr * di) * invd2;
            }
            float k00x[4], k00y[4], k01x[4], k01y[4];
            float k10x[4], k10y[4], k11x[4], k11y[4];
#pragma unroll
            for (int j = 0; j < 4; j++) {
                k00x[j] = 0.f; k00y[j] = 0.f; k01x[j] = 0.f; k01y[j] = 0.f;
                k10x[j] = 0.f; k10y[j] = 0.f; k11x[j] = 0.f; k11y[j] = 0.f;
            }
            for (int n = 0; n < Npol; n++) {
                float4 A = polA[n];
                float4 B = polB[n];
                float n11 = n11S[n];
#pragma unroll
                for (int j = 0; j < 4; j++) {
                    float er = gr[j] - A.x, ei = gi[j] - A.y;
                    float inv2 = fast_rcp(fmaf(er, er, ei * ei));
                    float ir = er * inv2;
                    float mi = ei * inv2;
                    k00x[j] = fmaf(A.z, ir, fmaf(A.w, mi, k00x[j]));
                    k00y[j] = fmaf(A.w, ir, fmaf(-A.z, mi, k00y[j]));
                    k01x[j] = fmaf(B.x, ir, fmaf(B.y, mi, k01x[j]));
                    k01y[j] = fmaf(B.y, ir, fmaf(-B.x, mi, k01y[j]));
                    k10x[j] = fmaf(B.z, ir, fmaf(B.w, mi, k10x[j]));
                    k10y[j] = fmaf(B.w, ir, fmaf(-B.z, mi, k10y[j]));
                    k11x[j] = fmaf(n11, ir, k11x[j]);
                    k11y[j] = fmaf(-n11, mi, k11y[j]);
                }
            }
#pragma unroll
            for (int j = 0; j < 4; j++) {
                int l = t + 512 * j;
                float dr = 1.0f + wrv[j], di = wiv[j];
                float invd2 = fast_rcp(dr * dr + di * di);
                float cr2 = 2.0f * dr * invd2, ci2 = -2.0f * di * invd2;
                float wr2 = 1.0f + k11x[j], wi2 = k11y[j];
                float w2inv = fast_rcp(fmaf(wr2, wr2, wi2 * wi2));
                float vr = wr2 * w2inv, vi = -wi2 * w2inv;
                float t1x = k01x[j] * k10x[j] - k01y[j] * k10y[j];
                float t1y = k01x[j] * k10y[j] + k01y[j] * k10x[j];
                float t2x = t1x * vr - t1y * vi, t2y = t1x * vi + t1y * vr;
                float ex = k00x[j] - t2x, ey = k00y[j] - t2y;
                data[sw(l)] = make_float2(cr2 * ex - ci2 * ey, cr2 * ey + ci2 * ex);
            }
        }
        __syncthreads();
        if (t < 128) {
            float2 v[16];
#pragma unroll
            for (int k = 0; k < 16; k++) v[k] = data[sw(t + 128 * k)];
            fft16_dif<true>(v);
#pragma unroll
            for (int i = 1; i < 16; i++) v[i] = cmulc(v[i], twget(tw, 2 * t * BR4[i]));
#pragma unroll
            for (int i = 0; i < 16; i++) data[sw(i * 128 + t)] = v[i];
        }
        __syncthreads();
        if (t < 128) {
            int i2 = t >> 3, j0 = t & 7;
            int base2 = i2 * 128 + j0;
            float2 v[16];
#pragma unroll
            for (int k = 0; k < 16; k++) v[k] = data[sw(base2 + 8 * k)];
            fft16_dif<true>(v);
#pragma unroll
            for (int i = 1; i < 16; i++) v[i] = cmulc(v[i], twget(tw, 32 * j0 * BR4[i]));
#pragma unroll
            for (int i = 0; i < 16; i++) data[sw(base2 + 8 * i)] = v[i];
        }
        __syncthreads();
        if (t < 256) {
            float2 v8[8];
#pragma unroll
            for (int k = 0; k < 8; k++) v8[k] = data[sw(t * 8 + k)];
            fft8_dif<true>(v8);
            int r = BR4[t >> 4], s = BR4[t & 15];
#pragma unroll
            for (int i = 0; i < 8; i++) {
                int l = r + 16 * s + 256 * BR3[i];
                ktmp[l] = v8[i].x * (1.0f / 2048.0f);
            }
        }
        __syncthreads();
        if (t < 256) {
            float2 vin[8];
#pragma unroll
            for (int k = 0; k < 8; k++) vin[k] = make_float2(ktmp[t + 256 * k], 0.f);
            fft4096_passA_hz(data, tw, t, vin);
        }
        __syncthreads();
        if (t < 256) fft4096_fwd_B(data, tw, t);
        __syncthreads();
        if (t < 256) fft4096_fwd_C(data, t);
        __syncthreads();
        float2* dst = Kd1 + ((size_t)layer * Hdim + hh) * 4096;
#pragma unroll
        for (int k = 0; k < 8; k++) {
            int p = t + 512 * k;
            dst[p] = data[sw(p)];
        }
    } else {
        // ---- encoder via bf16 MFMA + fused LN: 32 rows/block, t<256 active ----
        int r0 = (bid - 512) * 32;
        __bf16* ybf = (__bf16*)smem;              // 32*72 bf16
        float* dots = smem + 1152;                // 32*132 floats
        float2* mv = (float2*)(smem + 5376);      // 32 float2
        int bb = r0 >> 11, l0 = r0 & 2047;
        for (int i = t; i < 32 * 64; i += 512) {
            int r = i >> 6, k = i & 63;
            ybf[r * 72 + k] = (__bf16)x[(size_t)(r0 + r) * 64 + k];
        }
        __syncthreads();
        if (t < 256) {
            int wave = t >> 6, lane = t & 63;
            int m = lane & 31, half = lane >> 5;
            bf16x8 a[4];
#pragma unroll
            for (int kk = 0; kk < 4; kk++)
                a[kk] = *(const bf16x8*)&ybf[m * 72 + kk * 16 + half * 8];
            int o = 32 * wave + m;
            const __bf16* wr = encbf + (size_t)o * 64 + half * 8;
            f32x16 acc;
#pragma unroll
            for (int i = 0; i < 16; i++) acc[i] = 0.f;
#pragma unroll
            for (int kk = 0; kk < 4; kk++) {
                bf16x8 bw = *(const bf16x8*)(wr + kk * 16);
                acc = __builtin_amdgcn_mfma_f32_32x32x16_bf16(a[kk], bw, acc, 0, 0, 0);
            }
            float bo = enc_b[o];
#pragma unroll
            for (int reg = 0; reg < 16; reg++) {
                int row = (reg & 3) + 8 * (reg >> 2) + 4 * half;
                dots[row * 132 + o] = acc[reg] + bo;
            }
        }
        __syncthreads();
        if (t < 256) {
            int row = t >> 3, lane8 = t & 7;
            float s1 = 0.f, s2 = 0.f;
            int base = row * 132 + lane8 * 16;
#pragma unroll
            for (int q = 0; q < 4; q++) {
                float4 v4 = *(const float4*)&dots[base + 4 * q];
                s1 += v4.x + v4.y + v4.z + v4.w;
                s2 += v4.x * v4.x + v4.y * v4.y + v4.z * v4.z + v4.w * v4.w;
            }
#pragma unroll
            for (int mm = 1; mm < 8; mm <<= 1) { s1 += __shfl_xor(s1, mm); s2 += __shfl_xor(s2, mm); }
            if (lane8 == 0) {
                float mu = s1 * (1.0f / 128.0f);
                float var = s2 * (1.0f / 128.0f) - mu * mu;
                mv[row] = make_float2(mu, fast_rsq(var + 1e-5f));
            }
        }
        __syncthreads();
        if (t < 256) {
            int o2 = t & 127, rh = t >> 7;
            float nwc = nw[o2], nbc = nb[o2];
            float hnv[16];
#pragma unroll
            for (int j = 0; j < 16; j++) {
                int r = rh * 16 + j;
                float hvv = dots[r * 132 + o2];
                h[(size_t)(r0 + r) * Hdim + o2] = hvv;
                float2 mvv = mv[r];
                hnv[j] = (hvv - mvv.x) * mvv.y * nwc + nbc;
            }
            float* dst = hnT + ((size_t)bb * Hdim + o2) * Lseq + l0 + rh * 16;
            *(float4*)(dst)      = make_float4(hnv[0],  hnv[1],  hnv[2],  hnv[3]);
            *(float4*)(dst + 4)  = make_float4(hnv[4],  hnv[5],  hnv[6],  hnv[7]);
            *(float4*)(dst + 8)  = make_float4(hnv[8],  hnv[9],  hnv[10], hnv[11]);
            *(float4*)(dst + 12) = make_float4(hnv[12], hnv[13], hnv[14], hnv[15]);
        }
    }
}

// ---------------- FFT convolution: batch-pair packing, radix-16^3 ----------------
// Output y written as bf16 (its only consumer is the MLP's bf16 A-operand).
__global__ __launch_bounds__(256) void conv_kernel(const float* __restrict__ hnT,
                                                   __bf16* __restrict__ ybuf,
                                                   const float2* __restrict__ Kd1,
                                                   const float* __restrict__ dvec,
                                                   const float2* __restrict__ tw) {
    int h = blockIdx.x, bp = blockIdx.y, t = threadIdx.x;
    __shared__ float2 data[4096];
    const float* u0 = hnT + ((size_t)(2 * bp) * Hdim + h) * Lseq;
    const float* u1 = hnT + ((size_t)(2 * bp + 1) * Hdim + h) * Lseq;
    __bf16* y0 = ybuf + ((size_t)(2 * bp) * Hdim + h) * Lseq;
    __bf16* y1 = ybuf + ((size_t)(2 * bp + 1) * Hdim + h) * Lseq;
    float2 ureg[8];
    float2 Kreg[16];
    float2 twB[15];
    const int j0 = t & 15;
    const float4* Kp4 = (const float4*)(Kd1 + (size_t)h * 4096 + t * 16);
    {   // pruned pass A: input upper half zero, from registers. Kd + B-twiddle
        // prefetch issued alongside the u loads so latency hides under the fwd FFT.
        float2 vin[8];
#pragma unroll
        for (int k = 0; k < 8; k++) {
            int l = t + 256 * k;
            float2 u2 = make_float2(u0[l], u1[l]);
            ureg[k] = u2;
            vin[k] = u2;
        }
#pragma unroll
        for (int k = 0; k < 8; k++) {
            float4 q = Kp4[k];
            Kreg[2 * k]     = make_float2(q.x, q.y);
            Kreg[2 * k + 1] = make_float2(q.z, q.w);
        }
#pragma unroll
        for (int i = 1; i < 16; i++) twB[i - 1] = twget(tw, 16 * j0 * BR4[i]);
        fft4096_passA_hz(data, tw, t, vin);
    }
    __syncthreads();
    {   // forward pass B (register twiddles)
        int base = (t >> 4) * 256 + j0;
        float2 v[16];
#pragma unroll
        for (int k = 0; k < 16; k++) v[k] = data[sw(base + 16 * k)];
        fft16_dif<false>(v);
#pragma unroll
        for (int i = 1; i < 16; i++) v[i] = cmulf(v[i], twB[i - 1]);
#pragma unroll
        for (int i = 0; i < 16; i++) data[sw(base + 16 * i)] = v[i];
    }
    __syncthreads();
    {   // fused: forward pass C -> pointwise *Kd*scale -> inverse pass C'
        const float scale = 1.0f / 4096.0f;
        float2 v[16];
#pragma unroll
        for (int k = 0; k < 16; k++) v[k] = data[sw(t * 16 + k)];
        fft16_dif<false>(v);
#pragma unroll
        for (int i = 0; i < 16; i++) {
            float2 W = cmulf(v[i], Kreg[i]);
            v[i] = make_float2(W.x * scale, W.y * scale);
        }
        fft16_dit<true>(v);
#pragma unroll
        for (int i = 0; i < 16; i++) data[sw(t * 16 + i)] = v[i];
    }
    __syncthreads();
    {   // inverse pass B' (register twiddles, conjugated)
        int base2 = (t >> 4) * 256 + j0;
        float2 v[16];
        v[0] = data[sw(base2)];
#pragma unroll
        for (int i = 1; i < 16; i++)
            v[i] = cmulc(data[sw(base2 + 16 * i)], twB[i - 1]);
        fft16_dit<true>(v);
#pragma unroll
        for (int i = 0; i < 16; i++) data[sw(base2 + 16 * i)] = v[i];
    }
    __syncthreads();
    {   // inverse pass A': final stage pruned to the needed output half (l < 2048)
        float2 v[16];
        v[0] = data[sw(t)];
#pragma unroll
        for (int i = 1; i < 16; i++)
            v[i] = cmulc(data[sw(i * 256 + t)], twget(tw, t * BR4[i]));
#pragma unroll
        for (int mi = 3; mi >= 1; mi--) {
            const int m = 8 >> mi;
#pragma unroll
            for (int g = 0; g < 16; g += 2 * m) {
#pragma unroll
                for (int j = 0; j < m; j++) {
                    float wr = W16R[j << mi], wi = -W16I[j << mi];
                    float2 a = v[g + j], bb2 = v[g + j + m];
                    float bx = bb2.x * wr - bb2.y * wi, by = bb2.x * wi + bb2.y * wr;
                    v[g + j] = make_float2(a.x + bx, a.y + by);
                    v[g + j + m] = make_float2(a.x - bx, a.y - by);
                }
            }
        }
#pragma unroll
        for (int j = 0; j < 8; j++) {
            float wr = W16R[j], wi = -W16I[j];
            float2 bb2 = v[j + 8];
            float bx = bb2.x * wr - bb2.y * wi, by = bb2.x * wi + bb2.y * wr;
            v[j] = make_float2(v[j].x + bx, v[j].y + by);
        }
        float dcoef = dvec[h];
#pragma unroll
        for (int k = 0; k < 8; k++) {
            int l = t + 256 * k;
            y0[l] = (__bf16)gelu_f(v[k].x + ureg[k].x * dcoef);
            y1[l] = (__bf16)gelu_f(v[k].y + ureg[k].y * dcoef);
        }
    }
}

// ---------------- gated MLP via bf16 MFMA + residual + fused LN: 32 rows/block ----------------
__global__ __launch_bounds__(256) void mlp_kernel(const __bf16* __restrict__ yT,
                                                  float* __restrict__ h,
                                                  float* __restrict__ hnT,
                                                  const __bf16* __restrict__ w1b,
                                                  const __bf16* __restrict__ w2b,
                                                  const float* __restrict__ b1,
                                                  const float* __restrict__ b2,
                                                  const float* __restrict__ nw,
                                                  const float* __restrict__ nb) {
    int r0 = blockIdx.x * 32;
    int t = threadIdx.x;
    int wave = t >> 6, lane = t & 63;
    __shared__ __align__(16) __bf16 ybf[32 * 136];
    __shared__ float dots[32 * 132];
    __shared__ float2 mv[32];
    int bb = r0 >> 11, l0 = r0 & 2047;
    for (int i = t; i < 32 * 128; i += 256) {
        int r = i & 31, k = i >> 5;
        ybf[r * 136 + k] = yT[((size_t)bb * Hdim + k) * Lseq + l0 + r];
    }
    __syncthreads();
    int m = lane & 31, half = lane >> 5;
    bf16x8 a[8];
#pragma unroll
    for (int kk = 0; kk < 8; kk++)
        a[kk] = *(const bf16x8*)&ybf[m * 136 + kk * 16 + half * 8];
    int out = 32 * wave + m;
    const __bf16* w1r = w1b + (size_t)out * 128 + half * 8;
    const __bf16* w2r = w2b + (size_t)out * 128 + half * 8;
    f32x16 acc1, acc2;
#pragma unroll
    for (int i = 0; i < 16; i++) { acc1[i] = 0.f; acc2[i] = 0.f; }
#pragma unroll
    for (int kk = 0; kk < 8; kk++) {
        bf16x8 bw1 = *(const bf16x8*)(w1r + kk * 16);
        bf16x8 bw2 = *(const bf16x8*)(w2r + kk * 16);
        acc1 = __builtin_amdgcn_mfma_f32_32x32x16_bf16(a[kk], bw1, acc1, 0, 0, 0);
        acc2 = __builtin_amdgcn_mfma_f32_32x32x16_bf16(a[kk], bw2, acc2, 0, 0, 0);
    }
    float bias1 = b1[out], bias2 = b2[out];
#pragma unroll
    for (int reg = 0; reg < 16; reg++) {
        int row = (reg & 3) + 8 * (reg >> 2) + 4 * half;
        float v1 = acc1[reg] + bias1;
        float v2 = acc2[reg] + bias2;
        float g = fast_rcp(1.0f + __expf(-v2));
        float hv = h[(size_t)(r0 + row) * Hdim + out] + v1 * g;
        dots[row * 132 + out] = hv;
    }
    __syncthreads();
    {
        int row = t >> 3, lane8 = t & 7;
        float s1 = 0.f, s2 = 0.f;
        int base = row * 132 + lane8 * 16;
#pragma unroll
        for (int q = 0; q < 4; q++) {
            float4 v4 = *(const float4*)&dots[base + 4 * q];
            s1 += v4.x + v4.y + v4.z + v4.w;
            s2 += v4.x * v4.x + v4.y * v4.y + v4.z * v4.z + v4.w * v4.w;
        }
#pragma unroll
        for (int mm = 1; mm < 8; mm <<= 1) { s1 += __shfl_xor(s1, mm); s2 += __shfl_xor(s2, mm); }
        if (lane8 == 0) {
            float mu = s1 * (1.0f / 128.0f);
            float var = s2 * (1.0f / 128.0f) - mu * mu;
            mv[row] = make_float2(mu, fast_rsq(var + 1e-5f));
        }
    }
    __syncthreads();
    {
        int o = t & 127, rh = t >> 7;
        float nwc = nw[o], nbc = nb[o];
        float hnv[16];
#pragma unroll
        for (int j = 0; j < 16; j++) {
            int r = rh * 16 + j;
            float hvv = dots[r * 132 + o];
            h[(size_t)(r0 + r) * Hdim + o] = hvv;
            float2 mvv = mv[r];
            hnv[j] = (hvv - mvv.x) * mvv.y * nwc + nbc;
        }
        float* dst = hnT + ((size_t)bb * Hdim + o) * Lseq + l0 + rh * 16;
        *(float4*)(dst)      = make_float4(hnv[0],  hnv[1],  hnv[2],  hnv[3]);
        *(float4*)(dst + 4)  = make_float4(hnv[4],  hnv[5],  hnv[6],  hnv[7]);
        *(float4*)(dst + 8)  = make_float4(hnv[8],  hnv[9],  hnv[10], hnv[11]);
        *(float4*)(dst + 12) = make_float4(hnv[12], hnv[13], hnv[14], hnv[15]);
    }
}

// ---------------- last layer: gated MLP + residual + fused DECODER (bf16 MFMA) ----------
__global__ __launch_bounds__(256) void mlpdec_kernel(const __bf16* __restrict__ yT,
                                                     const float* __restrict__ h,
                                                     const __bf16* __restrict__ w1b,
                                                     const __bf16* __restrict__ w2b,
                                                     const float* __restrict__ b1,
                                                     const float* __restrict__ b2,
                                                     const __bf16* __restrict__ decb,
                                                     const float* __restrict__ dec_bias,
                                                     float* __restrict__ out) {
    int r0 = blockIdx.x * 32;
    int t = threadIdx.x;
    int wave = t >> 6, lane = t & 63;
    __shared__ __align__(16) __bf16 ybf[32 * 136];
    __shared__ float dots[32 * 132];
    int bb = r0 >> 11, l0 = r0 & 2047;
    for (int i = t; i < 32 * 128; i += 256) {
        int r = i & 31, k = i >> 5;
        ybf[r * 136 + k] = yT[((size_t)bb * Hdim + k) * Lseq + l0 + r];
    }
    __syncthreads();
    int m = lane & 31, half = lane >> 5;
    bf16x8 a[8];
#pragma unroll
    for (int kk = 0; kk < 8; kk++)
        a[kk] = *(const bf16x8*)&ybf[m * 136 + kk * 16 + half * 8];
    int outc = 32 * wave + m;
    const __bf16* w1r = w1b + (size_t)outc * 128 + half * 8;
    const __bf16* w2r = w2b + (size_t)outc * 128 + half * 8;
    f32x16 acc1, acc2;
#pragma unroll
    for (int i = 0; i < 16; i++) { acc1[i] = 0.f; acc2[i] = 0.f; }
#pragma unroll
    for (int kk = 0; kk < 8; kk++) {
        bf16x8 bw1 = *(const bf16x8*)(w1r + kk * 16);
        bf16x8 bw2 = *(const bf16x8*)(w2r + kk * 16);
        acc1 = __builtin_amdgcn_mfma_f32_32x32x16_bf16(a[kk], bw1, acc1, 0, 0, 0);
        acc2 = __builtin_amdgcn_mfma_f32_32x32x16_bf16(a[kk], bw2, acc2, 0, 0, 0);
    }
    float bias1 = b1[outc], bias2 = b2[outc];
#pragma unroll
    for (int reg = 0; reg < 16; reg++) {
        int row = (reg & 3) + 8 * (reg >> 2) + 4 * half;
        float v1 = acc1[reg] + bias1;
        float v2 = acc2[reg] + bias2;
        float g = fast_rcp(1.0f + __expf(-v2));
        float hv = h[(size_t)(r0 + row) * Hdim + outc] + v1 * g;
        dots[row * 132 + outc] = hv;
    }
    __syncthreads();
    // restage h tile as bf16 A-operands
    for (int i = t; i < 32 * 128; i += 256) {
        int r = i >> 7, k = i & 127;
        ybf[r * 136 + k] = (__bf16)dots[r * 132 + k];
    }
    __syncthreads();
    if (wave < 2) {  // decoder GEMM: 32 rows x 64 outs, K=128
        bf16x8 a2[8];
#pragma unroll
        for (int kk = 0; kk < 8; kk++)
            a2[kk] = *(const bf16x8*)&ybf[m * 136 + kk * 16 + half * 8];
        int oc = 32 * wave + m;  // 0..63
        const __bf16* wr = decb + (size_t)oc * 128 + half * 8;
        f32x16 acc;
#pragma unroll
        for (int i = 0; i < 16; i++) acc[i] = 0.f;
#pragma unroll
        for (int kk = 0; kk < 8; kk++) {
            bf16x8 bw = *(const bf16x8*)(wr + kk * 16);
            acc = __builtin_amdgcn_mfma_f32_32x32x16_bf16(a2[kk], bw, acc, 0, 0, 0);
        }
        float bo = dec_bias[oc];
#pragma unroll
        for (int reg = 0; reg < 16; reg++) {
            int row = (reg & 3) + 8 * (reg >> 2) + 4 * half;
            out[(size_t)(r0 + row) * 64 + oc] = acc[reg] + bo;
        }
    }
}

extern "C" void kernel_launch(void* const* d_in, const int* in_sizes, int n_in,
                              void* d_out, int out_size, void* d_ws, size_t ws_size,
                              hipStream_t stream) {
    const float* x      = (const float*)d_in[0];
    const float* enc_w  = (const float*)d_in[2];
    const float* enc_b  = (const float*)d_in[3];
    const float* dec_w  = (const float*)d_in[4];
    const float* dec_b  = (const float*)d_in[5];
    const float* lam_re = (const float*)d_in[6];
    const float* lam_im = (const float*)d_in[7];
    const float* p_re   = (const float*)d_in[8];
    const float* p_im   = (const float*)d_in[9];
    const float* b_re   = (const float*)d_in[10];
    const float* b_im   = (const float*)d_in[11];
    const float* c_re   = (const float*)d_in[12];
    const float* c_im   = (const float*)d_in[13];
    const float* dvec   = (const float*)d_in[14];
    const float* lstep  = (const float*)d_in[15];
    const float* norm_w = (const float*)d_in[16];
    const float* norm_b = (const float*)d_in[17];
    const float* w1     = (const float*)d_in[18];
    const float* b1     = (const float*)d_in[19];
    const float* w2     = (const float*)d_in[20];
    const float* b2     = (const float*)d_in[21];
    float* out = (float*)d_out;

    char* ws = (char*)d_ws;
    float2* tw  = (float2*)ws;  ws += 2048 * sizeof(float2);
    float*  h   = (float*)ws;   ws += (size_t)Bsz * Lseq * Hdim * sizeof(float);
    float*  hnT = (float*)ws;   ws += (size_t)Bsz * Lseq * Hdim * sizeof(float);
    __bf16* ybuf = (__bf16*)ws; ws += (size_t)Bsz * Lseq * Hdim * sizeof(__bf16);
    float2* Kd1 = (float2*)ws;  ws += (size_t)NLAYERS * Hdim * 4096 * sizeof(float2);
    __bf16* wbf = (__bf16*)ws;  ws += (size_t)NLAYERS * 2 * Hdim * Hdim * sizeof(__bf16);
    __bf16* dbf = (__bf16*)ws;  ws += (size_t)64 * Hdim * sizeof(__bf16);
    __bf16* ebf = (__bf16*)ws;  ws += (size_t)Hdim * 64 * sizeof(__bf16);

    const int nrows = Bsz * Lseq;  // 16384

    prep_kernel<<<328, 256, 0, stream>>>(w1, w2, dec_w, enc_w, tw, wbf, dbf, ebf);
    kfft_enc_kernel<<<512 + nrows / 32, 512, 0, stream>>>(
        Kd1, tw, x, ebf, enc_b, norm_w, norm_b, h, hnT,
        lam_re, lam_im, p_re, p_im, b_re, b_im, c_re, c_im, lstep);
    for (int L = 0; L < NLAYERS; L++) {
        conv_kernel<<<dim3(Hdim, Bsz / 2), 256, 0, stream>>>(
            hnT, ybuf, Kd1 + (size_t)L * Hdim * 4096, dvec + L * Hdim, tw);
        const __bf16* w1bL = wbf + (size_t)L * 2 * Hdim * Hdim;
        const __bf16* w2bL = w1bL + Hdim * Hdim;
        if (L < NLAYERS - 1) {
            const float* nwn = norm_w + (L + 1) * Hdim;
            const float* nbn = norm_b + (L + 1) * Hdim;
            mlp_kernel<<<nrows / 32, 256, 0, stream>>>(ybuf, h, hnT, w1bL, w2bL,
                                                       b1 + L * Hdim, b2 + L * Hdim,
                                                       nwn, nbn);
        } else {
            mlpdec_kernel<<<nrows / 32, 256, 0, stream>>>(ybuf, h, w1bL, w2bL,
                                                          b1 + L * Hdim, b2 + L * Hdim,
                                                          dbf, dec_b, out);
        }
    }
}